// Round 4
// baseline (2750.530 us; speedup 1.0000x reference)
//
#include <hip/hip_runtime.h>

#define N_NODES 65536
#define N_EDGES 262144

typedef unsigned short u16;
typedef unsigned char u8;
typedef float f32x4 __attribute__((ext_vector_type(4)));
typedef _Float16 h2 __attribute__((ext_vector_type(2)));
typedef _Float16 v8h __attribute__((ext_vector_type(8)));

__device__ __forceinline__ u16 f2h(float f) {
  return __builtin_bit_cast(u16, (_Float16)f);
}
// 8-bit e5m2 == top byte of fp16 with RNE rounding.
__device__ __forceinline__ u8 f2e5m2(float f) {
  _Float16 h = (_Float16)f;
  u16 hb = __builtin_bit_cast(u16, h);
  hb = (u16)(hb + 0x7F + ((hb >> 8) & 1));
  return (u8)(hb >> 8);
}
// decode dword = 4 e5m2 bytes -> 4 floats (node_gather)
__device__ __forceinline__ void dec4(unsigned d, float* o) {
  o[0] = (float)__builtin_bit_cast(_Float16, (u16)((d << 8) & 0xFF00u));
  o[1] = (float)__builtin_bit_cast(_Float16, (u16)(d & 0xFF00u));
  o[2] = (float)__builtin_bit_cast(_Float16, (u16)((d >> 8) & 0xFF00u));
  o[3] = (float)__builtin_bit_cast(_Float16, (u16)((d >> 16) & 0xFF00u));
}
// e5m2 bytes (b0,b1) of dword -> fp16 pair via one v_perm
__device__ __forceinline__ h2 e5lo(unsigned d) {
  return __builtin_bit_cast(h2, __builtin_amdgcn_perm(d, 0u, 0x05000400u));
}
__device__ __forceinline__ h2 e5hi(unsigned d) {
  return __builtin_bit_cast(h2, __builtin_amdgcn_perm(d, 0u, 0x07000600u));
}
// sigmoid-form gelu: x - x/(1+exp(1.702x)); ~6 VALU ops
__device__ __forceinline__ float gelu_s(float x) {
  float e = __expf(1.702f * x);
  return x - __fdividef(x, e + 1.0f);
}
// tanh-form gelu (node f-MLP epilogue)
__device__ __forceinline__ float gelu_f(float x) {
  float y = 1.5957691216057308f * (x + 0.044715f * x * x * x);
  float e = __expf(y);
  return x - __fdividef(x, e + 1.0f);
}
// async global->LDS, 16 bytes per lane; LDS dest is wave-uniform base + lane*16
__device__ __forceinline__ void gld16(const u16* g, u16* l) {
  __builtin_amdgcn_global_load_lds(
      (const __attribute__((address_space(1))) void*)g,
      (__attribute__((address_space(3))) void*)l, 16, 0, 0);
}

// ---------------- LayerNorm -> fp16 ----------------
__global__ __launch_bounds__(256) void ln_kernel(const float* __restrict__ x,
                                                 const float* __restrict__ g,
                                                 const float* __restrict__ b,
                                                 u16* __restrict__ out) {
  int row = blockIdx.x * 4 + (threadIdx.x >> 6);
  int lane = threadIdx.x & 63;
  float4 v = ((const float4*)(x + (size_t)row * 256))[lane];
  float s = v.x + v.y + v.z + v.w;
  float s2 = v.x * v.x + v.y * v.y + v.z * v.z + v.w * v.w;
#pragma unroll
  for (int off = 1; off < 64; off <<= 1) {
    s += __shfl_xor(s, off, 64);
    s2 += __shfl_xor(s2, off, 64);
  }
  float mean = s * (1.0f / 256.0f);
  float var = s2 * (1.0f / 256.0f) - mean * mean;
  float rs = rsqrtf(var + 1e-5f);
  float4 gv = ((const float4*)g)[lane];
  float4 bv = ((const float4*)b)[lane];
  ushort4 o;
  o.x = f2h((v.x - mean) * rs * gv.x + bv.x);
  o.y = f2h((v.y - mean) * rs * gv.y + bv.y);
  o.z = f2h((v.z - mean) * rs * gv.z + bv.z);
  o.w = f2h((v.w - mean) * rs * gv.w + bv.w);
  *(ushort4*)(out + (size_t)row * 256 + lane * 4) = o;
}

// ---------------- generic fp16 GEMM (round-0 gemm_bt: best measured for small node GEMMs)
template <typename Epi>
__global__ __launch_bounds__(256) void gemm_bt(const u16* __restrict__ A,
                                               const u16* __restrict__ BT,
                                               int K, Epi epi) {
  __shared__ __align__(16) u16 sA[128 * 48];
  __shared__ __align__(16) u16 sB[128 * 48];
  const int tm = blockIdx.x * 128, tn = blockIdx.y * 128;
  const int t = threadIdx.x;
  const int wave = t >> 6, lane = t & 63;
  const int lrow = lane & 15, quad = lane >> 4;
  const int wrow = (wave & 1) * 64, wcol = (wave >> 1) * 64;
  const int r = t >> 2, c = (t & 3) << 3;
  f32x4 acc[4][4];
  const f32x4 z = {0.f, 0.f, 0.f, 0.f};
#pragma unroll
  for (int i = 0; i < 4; ++i)
#pragma unroll
    for (int j = 0; j < 4; ++j) acc[i][j] = z;
  for (int k0 = 0; k0 < K; k0 += 32) {
    *(uint4*)&sA[r * 48 + c] = *(const uint4*)&A[(size_t)(tm + r) * K + k0 + c];
    *(uint4*)&sA[(r + 64) * 48 + c] = *(const uint4*)&A[(size_t)(tm + r + 64) * K + k0 + c];
    *(uint4*)&sB[r * 48 + c] = *(const uint4*)&BT[(size_t)(tn + r) * K + k0 + c];
    *(uint4*)&sB[(r + 64) * 48 + c] = *(const uint4*)&BT[(size_t)(tn + r + 64) * K + k0 + c];
    __syncthreads();
    v8h af[4], bfv[4];
#pragma unroll
    for (int i = 0; i < 4; ++i) af[i] = *(const v8h*)&sA[(wrow + i * 16 + lrow) * 48 + quad * 8];
#pragma unroll
    for (int j = 0; j < 4; ++j) bfv[j] = *(const v8h*)&sB[(wcol + j * 16 + lrow) * 48 + quad * 8];
#pragma unroll
    for (int i = 0; i < 4; ++i)
#pragma unroll
      for (int j = 0; j < 4; ++j)
        acc[i][j] = __builtin_amdgcn_mfma_f32_16x16x32_f16(af[i], bfv[j], acc[i][j], 0, 0, 0);
    __syncthreads();
  }
#pragma unroll
  for (int i = 0; i < 4; ++i)
#pragma unroll
    for (int j = 0; j < 4; ++j)
#pragma unroll
      for (int rg = 0; rg < 4; ++rg)
        epi(tm + wrow + i * 16 + quad * 4 + rg, tn + wcol + j * 16 + lrow, acc[i][j][rg]);
}

// ---------------- AB GEMM core (128x128 tile, BK=32, double-buffered gload_lds) --------
#define GEMM_DBUF(K_)                                                                    \
  const int t = threadIdx.x;                                                             \
  const int wave = t >> 6, lane = t & 63;                                                \
  const int lrow = lane & 15, quad = lane >> 4;                                          \
  const int wrow = (wave & 1) * 64, wcol = (wave >> 1) * 64;                             \
  const int sa0 = 2 * wave, sa1 = 2 * wave + 1;                                          \
  const u16* pa0 = A + (size_t)(tm + sa0 * 16 + lrow) * (K_) + quad * 8;                 \
  const u16* pa1 = A + (size_t)(tm + sa1 * 16 + lrow) * (K_) + quad * 8;                 \
  const u16* pb0 = BT + (size_t)(tn + sa0 * 16 + lrow) * (K_) + quad * 8;                \
  const u16* pb1 = BT + (size_t)(tn + sa1 * 16 + lrow) * (K_) + quad * 8;                \
  f32x4 acc[4][4];                                                                       \
  {                                                                                      \
    const f32x4 z = {0.f, 0.f, 0.f, 0.f};                                                \
    _Pragma("unroll") for (int i = 0; i < 4; ++i)                                        \
        _Pragma("unroll") for (int j = 0; j < 4; ++j) acc[i][j] = z;                     \
  }                                                                                      \
  gld16(pa0, &sAB[sa0 * 512]);                                                           \
  gld16(pa1, &sAB[sa1 * 512]);                                                           \
  gld16(pb0, &sAB[4096 + sa0 * 512]);                                                    \
  gld16(pb1, &sAB[4096 + sa1 * 512]);                                                    \
  pa0 += 32; pa1 += 32; pb0 += 32; pb1 += 32;                                            \
  __syncthreads();                                                                       \
  int cur = 0;                                                                           \
  _Pragma("unroll") for (int k0 = 32; k0 < (K_); k0 += 32) {                             \
    const int nxt = cur ^ 1;                                                             \
    gld16(pa0, &sAB[nxt * 8192 + sa0 * 512]);                                            \
    gld16(pa1, &sAB[nxt * 8192 + sa1 * 512]);                                            \
    gld16(pb0, &sAB[nxt * 8192 + 4096 + sa0 * 512]);                                     \
    gld16(pb1, &sAB[nxt * 8192 + 4096 + sa1 * 512]);                                     \
    pa0 += 32; pa1 += 32; pb0 += 32; pb1 += 32;                                          \
    v8h af[4], bfv[4];                                                                   \
    _Pragma("unroll") for (int i = 0; i < 4; ++i) af[i] =                                \
        *(const v8h*)&sAB[cur * 8192 + ((wave & 1) * 4 + i) * 512 + lane * 8];           \
    _Pragma("unroll") for (int j = 0; j < 4; ++j) bfv[j] =                               \
        *(const v8h*)&sAB[cur * 8192 + 4096 + ((wave >> 1) * 4 + j) * 512 + lane * 8];   \
    _Pragma("unroll") for (int i = 0; i < 4; ++i)                                        \
        _Pragma("unroll") for (int j = 0; j < 4; ++j) acc[i][j] =                        \
            __builtin_amdgcn_mfma_f32_16x16x32_f16(af[i], bfv[j], acc[i][j], 0, 0, 0);   \
    __syncthreads();                                                                     \
    cur = nxt;                                                                           \
  }                                                                                      \
  {                                                                                      \
    v8h af[4], bfv[4];                                                                   \
    _Pragma("unroll") for (int i = 0; i < 4; ++i) af[i] =                                \
        *(const v8h*)&sAB[cur * 8192 + ((wave & 1) * 4 + i) * 512 + lane * 8];           \
    _Pragma("unroll") for (int j = 0; j < 4; ++j) bfv[j] =                               \
        *(const v8h*)&sAB[cur * 8192 + 4096 + ((wave >> 1) * 4 + j) * 512 + lane * 8];   \
    _Pragma("unroll") for (int i = 0; i < 4; ++i)                                        \
        _Pragma("unroll") for (int j = 0; j < 4; ++j) acc[i][j] =                        \
            __builtin_amdgcn_mfma_f32_16x16x32_f16(af[i], bfv[j], acc[i][j], 0, 0, 0);   \
  }

// specialized AB GEMM: M=65536, N=3072, K=256; e5m2 byte output staged through LDS
// (stride 136 -> quads land in disjoint bank groups), XCD-chunked swizzle.
__global__ __launch_bounds__(256) void gemm2_ab(const u16* __restrict__ A,
                                                const u16* __restrict__ BT,
                                                const float* __restrict__ b1cat,
                                                u8* __restrict__ out) {
  __shared__ __align__(16) u16 sAB[16384];
  const int bid = blockIdx.x;  // 12288 = 8 xcd * 64 mt * 24 nt
  const int local = bid >> 3;
  const int mt = (bid & 7) * 64 + local / 24;
  const int nt = local % 24;
  const int tm = mt * 128, tn = nt * 128;
  GEMM_DBUF(256)
  __syncthreads();  // last-tile LDS reads must drain before sAB reuse
  float bj[4];
#pragma unroll
  for (int j = 0; j < 4; ++j)
    bj[j] = (nt < 12) ? b1cat[tn + wcol + j * 16 + lrow] : 0.f;
  u8* sb = (u8*)sAB;
#pragma unroll
  for (int i = 0; i < 4; ++i)
#pragma unroll
    for (int j = 0; j < 4; ++j)
#pragma unroll
      for (int rg = 0; rg < 4; ++rg)
        sb[(wrow + i * 16 + quad * 4 + rg) * 136 + wcol + j * 16 + lrow] =
            f2e5m2(acc[i][j][rg] + bj[j]);
  __syncthreads();
  {
    int ir = t >> 1, sg = t & 1;
    const u8* srcp = &sb[ir * 136 + sg * 64];
    uint2* dstp = (uint2*)(out + (size_t)(tm + ir) * 3072 + tn + sg * 64);
#pragma unroll
    for (int q = 0; q < 8; ++q) dstp[q] = *(const uint2*)(srcp + q * 8);
  }
}

struct EpiX2 {
  float* x2;
  const float* x1;
  const float* rb;
  __device__ void operator()(int m, int n, float v) const {
    x2[(size_t)m * 256 + n] = v + rb[n] + x1[(size_t)m * 256 + n];
  }
};
struct EpiHf {
  u16* hf;
  const float* b1;
  __device__ void operator()(int m, int n, float v) const {
    hf[(size_t)m * 512 + n] = f2h(gelu_f(v + b1[n]));
  }
};
struct EpiOut {
  float* out;
  const float* b2;
  const float* x2;
  __device__ void operator()(int m, int n, float v) const {
    out[(size_t)m * 256 + n] = v + b2[n] + x2[(size_t)m * 256 + n];
  }
};

// ---------------- weight repacks ----------------
__global__ void prep_w1catT(u16* __restrict__ out, const float* __restrict__ qW1,
                            const float* __restrict__ kW1, const float* __restrict__ vW1) {
  int cIdx = blockIdx.x;
  int rIdx = threadIdx.x;
  int sec = cIdx >> 9;
  int h = cIdx & 511;
  int mlp = sec % 3;
  const float* W1 = (mlp == 0) ? qW1 : (mlp == 1) ? kW1 : vW1;
  int rowoff = (sec < 3) ? 0 : 256;
  out[(size_t)cIdx * 256 + rIdx] = f2h(W1[(size_t)(rowoff + rIdx) * 512 + h]);
}
__global__ void prep_w2T(u16* __restrict__ out, const float* __restrict__ qW2,
                         const float* __restrict__ kW2, const float* __restrict__ vW2) {
  int row = blockIdx.x;
  int m = row >> 8, n = row & 255;
  const float* W2 = (m == 0) ? qW2 : (m == 1) ? kW2 : vW2;
  for (int k = threadIdx.x; k < 512; k += 256)
    out[(size_t)row * 512 + k] = f2h(W2[(size_t)k * 256 + n]);
}
__global__ void transpose_cast(u16* __restrict__ out, const float* __restrict__ in, int K, int Nn) {
  int n = blockIdx.x;
  for (int k = threadIdx.x; k < K; k += blockDim.x)
    out[(size_t)n * K + k] = f2h(in[(size_t)k * Nn + n]);
}
__global__ void prep_w1e16(u16* __restrict__ out, const float* __restrict__ qW1,
                           const float* __restrict__ kW1, const float* __restrict__ vW1) {
  int b = blockIdx.x;  // m*3 + r
  int m = b / 3, r = b % 3;
  const float* W1 = (m == 0) ? qW1 : (m == 1) ? kW1 : vW1;
  out[(size_t)b * 512 + threadIdx.x] = f2h(W1[(size_t)(512 + r) * 512 + threadIdx.x]);
}
__global__ void prep_b1cat(float* __restrict__ out, const float* __restrict__ qb1,
                           const float* __restrict__ kb1, const float* __restrict__ vb1) {
  int idx = blockIdx.x * 256 + threadIdx.x;  // 1536
  const float* b = (idx < 512) ? qb1 : (idx < 1024) ? kb1 : vb1;
  out[idx] = b[idx & 511];
}

// ---------------- s-MLP bias precompute: bias[e][h], one thread per edge ----------------
__global__ __launch_bounds__(256) void bias_kernel(const float* __restrict__ eattr,
                                                   const float* __restrict__ sW1,
                                                   const float* __restrict__ sb1,
                                                   const float* __restrict__ sW2,
                                                   const float* __restrict__ sb2,
                                                   float* __restrict__ biasb) {
  int e = blockIdx.x * 256 + threadIdx.x;
  const float* ea = eattr + (size_t)e * 7;
  float a0 = ea[3], a1 = ea[4], a2 = ea[5], a3 = ea[6];
  float acc[8];
#pragma unroll
  for (int h = 0; h < 8; ++h) acc[h] = sb2[h];
#pragma unroll 4
  for (int j = 0; j < 64; ++j) {
    float zz = fmaxf(a0 * sW1[j] + a1 * sW1[64 + j] + a2 * sW1[128 + j] + a3 * sW1[192 + j] + sb1[j], 0.f);
#pragma unroll
    for (int h = 0; h < 8; ++h) acc[h] += zz * sW2[j * 8 + h];
  }
  float4* bp = (float4*)(biasb + (size_t)e * 8);
  float4 v0 = {acc[0], acc[1], acc[2], acc[3]};
  float4 v1 = {acc[4], acc[5], acc[6], acc[7]};
  bp[0] = v0;
  bp[1] = v1;
}

// ---------------- CSR build ----------------
__global__ __launch_bounds__(256) void hist_kernel(const int* __restrict__ dst,
                                                   unsigned* __restrict__ cnt) {
  int e = blockIdx.x * 256 + threadIdx.x;
  atomicAdd(&cnt[dst[e]], 1u);
}
__global__ __launch_bounds__(1024) void scan_kernel(const unsigned* __restrict__ cnt,
                                                    unsigned* __restrict__ off,
                                                    unsigned* __restrict__ woff) {
  __shared__ unsigned s_part[1024];
  int t = threadIdx.x;
  unsigned local[64];
  unsigned run = 0;
  const uint4* cp = (const uint4*)(cnt + t * 64);
#pragma unroll
  for (int j = 0; j < 16; ++j) {
    uint4 v = cp[j];
    local[j * 4 + 0] = v.x; local[j * 4 + 1] = v.y;
    local[j * 4 + 2] = v.z; local[j * 4 + 3] = v.w;
  }
#pragma unroll
  for (int j = 0; j < 64; ++j) { unsigned c = local[j]; local[j] = run; run += c; }
  s_part[t] = run;
  __syncthreads();
  for (int d = 1; d < 1024; d <<= 1) {
    unsigned v = (t >= d) ? s_part[t - d] : 0u;
    __syncthreads();
    s_part[t] += v;
    __syncthreads();
  }
  unsigned base = (t == 0) ? 0u : s_part[t - 1];
  for (int j = 0; j < 64; ++j) {
    unsigned o = base + local[j];
    off[t * 64 + j] = o;
    woff[t * 64 + j] = o;
  }
}
__global__ __launch_bounds__(256) void scatter_ids(const int* __restrict__ dst,
                                                   unsigned* __restrict__ woff,
                                                   unsigned* __restrict__ eid) {
  int e = blockIdx.x * 256 + threadIdx.x;
  unsigned pos = atomicAdd(&woff[dst[e]], 1u);
  eid[pos] = (unsigned)e;
}

// ---------------- fused QKV GEMM + attention: 64 edges/block (dst-sorted), one dispatch --
// Edges processed in eid (dst-sorted) order: dst-half AB gathers cluster (~4 edges/node ->
// L1/L2 hits) and wv is written at the SORTED position so node_gather streams it.
// Register-prefetch pipeline: chunk c+1's 4 global_load_dwordx4 issue before assemble(c),
// so gather latency hides under the assemble VALU instead of serializing.
__global__ __launch_bounds__(256) void qkv_attn(
    const int* __restrict__ eidx, const float* __restrict__ eattr,
    const unsigned* __restrict__ eid,
    const u8* __restrict__ AB, const u16* __restrict__ W2T, const u16* __restrict__ w1e16,
    const float* __restrict__ qb2, const float* __restrict__ kb2, const float* __restrict__ vb2,
    const float* __restrict__ biasb, u8* __restrict__ wv) {
  __shared__ __align__(16) u8 sQ[64][784];  // e5m2 q|k|v per edge, stride 784 (bank spread)
  __shared__ __align__(16) u8 sRaw[17408];  // sH (GEMM phase) / sS (attn phase)
  __shared__ int s_src[64], s_dst[64];
  __shared__ unsigned s_eid[64];
  __shared__ __align__(16) float s_ea[64][4];
  u16(*sH)[136] = (u16(*)[136])sRaw;
  float(*sS)[8][8] = (float(*)[8][8])sRaw;
  const int t = threadIdx.x;
  const int e0 = blockIdx.x * 64;
  if (t < 64) {
    unsigned e = eid[e0 + t];
    s_eid[t] = e;
    s_src[t] = eidx[e];
    s_dst[t] = eidx[N_EDGES + e];
    const float* ea = eattr + (size_t)e * 7;
    s_ea[t][0] = ea[0]; s_ea[t][1] = ea[1]; s_ea[t][2] = ea[2];
  }
  __syncthreads();
  const int i = t & 63, seg = t >> 6;
  const int lane = t & 63, wave = t >> 6;
  const int lrow = lane & 15, quad = lane >> 4;
  const int wrow = (wave & 1) * 32, wcol = (wave >> 1) * 128;
  h2 ea0h, ea1h, ea2h;
  ea0h[0] = ea0h[1] = (_Float16)s_ea[i][0];
  ea1h[0] = ea1h[1] = (_Float16)s_ea[i][1];
  ea2h[0] = ea2h[1] = (_Float16)s_ea[i][2];
  const u8* ABs = AB + (size_t)s_src[i] * 3072 + seg * 32;
  const u8* ABd = AB + (size_t)s_dst[i] * 3072 + 1536 + seg * 32;
  // register-prefetch pipeline over flat chunks c = m*4 + q (12 chunks, fully unrolled)
  uint4 cs0, cs1, cd0, cd1, ns0, ns1, nd0, nd1;
  cs0 = *(const uint4*)(ABs);
  cs1 = *(const uint4*)(ABs + 16);
  cd0 = *(const uint4*)(ABd);
  cd1 = *(const uint4*)(ABd + 16);
#pragma unroll
  for (int m = 0; m < 3; ++m) {
    const unsigned* w32 = (const unsigned*)(w1e16 + (size_t)m * 1536);
    const u16* Wm = W2T + (size_t)(m * 256 + wcol) * 512;
    f32x4 acc[2][8];
    {
      const f32x4 z = {0.f, 0.f, 0.f, 0.f};
#pragma unroll
      for (int i2 = 0; i2 < 2; ++i2)
#pragma unroll
        for (int j = 0; j < 8; ++j) acc[i2][j] = z;
    }
#pragma unroll
    for (int q = 0; q < 4; ++q) {
      const int c = m * 4 + q;
      const int k0 = q * 128;
      if (c < 11) {  // issue next chunk's gathers (latency hides under assemble below)
        const int cn = c + 1;
        const u8* ps = ABs + (cn >> 2) * 512 + (cn & 3) * 128;
        const u8* pd = ABd + (cn >> 2) * 512 + (cn & 3) * 128;
        ns0 = *(const uint4*)(ps);
        ns1 = *(const uint4*)(ps + 16);
        nd0 = *(const uint4*)(pd);
        nd1 = *(const uint4*)(pd + 16);
      }
      {  // assemble 32 cols per thread: edge i, cols [k0+seg*32, +32) from prefetched regs
        alignas(16) unsigned sd[8], dd[8];
        *(uint4*)&sd[0] = cs0;
        *(uint4*)&sd[4] = cs1;
        *(uint4*)&dd[0] = cd0;
        *(uint4*)&dd[4] = cd1;
        const int cp0 = (k0 + seg * 32) >> 1;
        alignas(16) unsigned hout[16];
#pragma unroll
        for (int d = 0; d < 8; ++d) {
          int cp = cp0 + d * 2;
          h2 slo = e5lo(sd[d]) + e5lo(dd[d]);
          h2 shi = e5hi(sd[d]) + e5hi(dd[d]);
          slo += ea0h * __builtin_bit_cast(h2, w32[cp]);
          shi += ea0h * __builtin_bit_cast(h2, w32[cp + 1]);
          slo += ea1h * __builtin_bit_cast(h2, w32[256 + cp]);
          shi += ea1h * __builtin_bit_cast(h2, w32[256 + cp + 1]);
          slo += ea2h * __builtin_bit_cast(h2, w32[512 + cp]);
          shi += ea2h * __builtin_bit_cast(h2, w32[512 + cp + 1]);
          float g0 = gelu_s((float)slo[0]), g1 = gelu_s((float)slo[1]);
          float g2 = gelu_s((float)shi[0]), g3 = gelu_s((float)shi[1]);
          hout[d * 2] = (unsigned)f2h(g0) | ((unsigned)f2h(g1) << 16);
          hout[d * 2 + 1] = (unsigned)f2h(g2) | ((unsigned)f2h(g3) << 16);
        }
        uint4* hp = (uint4*)&sH[i][seg * 32];
        hp[0] = *(const uint4*)&hout[0];
        hp[1] = *(const uint4*)&hout[4];
        hp[2] = *(const uint4*)&hout[8];
        hp[3] = *(const uint4*)&hout[12];
      }
      __syncthreads();
#pragma unroll
      for (int ks = 0; ks < 4; ++ks) {
        int kk = ks * 32;
        v8h a0 = *(const v8h*)&sH[wrow + lrow][kk + quad * 8];
        v8h a1 = *(const v8h*)&sH[wrow + 16 + lrow][kk + quad * 8];
#pragma unroll
        for (int j = 0; j < 8; ++j) {
          v8h b = *(const v8h*)&Wm[(size_t)(j * 16 + lrow) * 512 + k0 + kk + quad * 8];
          acc[0][j] = __builtin_amdgcn_mfma_f32_16x16x32_f16(a0, b, acc[0][j], 0, 0, 0);
          acc[1][j] = __builtin_amdgcn_mfma_f32_16x16x32_f16(a1, b, acc[1][j], 0, 0, 0);
        }
      }
      __syncthreads();
      cs0 = ns0; cs1 = ns1; cd0 = nd0; cd1 = nd1;
    }
    // epilogue: +b2, e5m2-encode into sQ (this m's 256-byte slice)
    const float* b2 = (m == 0) ? qb2 : (m == 1) ? kb2 : vb2;
#pragma unroll
    for (int i2 = 0; i2 < 2; ++i2)
#pragma unroll
      for (int j = 0; j < 8; ++j)
#pragma unroll
        for (int rg = 0; rg < 4; ++rg) {
          int row = wrow + i2 * 16 + quad * 4 + rg;
          int col = wcol + j * 16 + lrow;
          sQ[row][m * 256 + col] = f2e5m2(acc[i2][j][rg] + b2[col]);
        }
  }
  __syncthreads();  // sQ complete; sH dead -> sS aliases it
  // ---------------- attention phase: 8 threads/edge, 2 halves of 32 edges ----------------
  const int hh = t & 7, ib = t >> 3;
#pragma unroll
  for (int half = 0; half < 2; ++half) {
    const int ii = ib + half * 32;
    alignas(16) unsigned qd[8];
    *(uint4*)&qd[0] = *(const uint4*)&sQ[ii][hh * 32];
    *(uint4*)&qd[4] = *(const uint4*)&sQ[ii][hh * 32 + 16];
    h2 qh[16];
#pragma unroll
    for (int d = 0; d < 8; ++d) { qh[d * 2] = e5lo(qd[d]); qh[d * 2 + 1] = e5hi(qd[d]); }
    float bias = biasb[(size_t)s_eid[ii] * 8 + hh];
    float sc[8];
#pragma unroll
    for (int g = 0; g < 8; ++g) {
      alignas(16) unsigned kd[8];
      *(uint4*)&kd[0] = *(const uint4*)&sQ[ii][256 + g * 32];
      *(uint4*)&kd[4] = *(const uint4*)&sQ[ii][256 + g * 32 + 16];
      h2 acc;
      acc[0] = acc[1] = (_Float16)0.f;
#pragma unroll
      for (int d = 0; d < 8; ++d) {
        acc += qh[d * 2] * e5lo(kd[d]);
        acc += qh[d * 2 + 1] * e5hi(kd[d]);
      }
      sc[g] = (float)acc[0] + (float)acc[1];
    }
#pragma unroll
    for (int g = 0; g < 8; ++g) sS[ii][hh][g] = sc[g] * 0.17677669529663687f + bias;
  }
  __syncthreads();
#pragma unroll
  for (int half = 0; half < 2; ++half) {  // softmax over h (axis=1) per (edge, g=hh)
    const int ii = ib + half * 32;
    const int g = hh;
    float mx = -1e30f;
#pragma unroll
    for (int h2i = 0; h2i < 8; ++h2i) mx = fmaxf(mx, sS[ii][h2i][g]);
    float ev[8], ssum = 0.f;
#pragma unroll
    for (int h2i = 0; h2i < 8; ++h2i) {
      ev[h2i] = __expf(sS[ii][h2i][g] - mx);
      ssum += ev[h2i];
    }
    float inv = 1.0f / ssum;
#pragma unroll
    for (int h2i = 0; h2i < 8; ++h2i) sS[ii][h2i][g] = ev[h2i] * inv;
  }
  __syncthreads();
#pragma unroll
  for (int half = 0; half < 2; ++half) {  // wv[sorted pos][hh*32..] = sum_g attn*V
    const int ii = ib + half * 32;
    h2 va[16];
#pragma unroll
    for (int u = 0; u < 16; ++u) va[u][0] = va[u][1] = (_Float16)0.f;
#pragma unroll
    for (int g = 0; g < 8; ++g) {
      float at = sS[ii][hh][g];
      h2 at2;
      at2[0] = at2[1] = (_Float16)at;
      alignas(16) unsigned vd[8];
      *(uint4*)&vd[0] = *(const uint4*)&sQ[ii][512 + g * 32];
      *(uint4*)&vd[4] = *(const uint4*)&sQ[ii][512 + g * 32 + 16];
#pragma unroll
      for (int d = 0; d < 8; ++d) {
        va[d * 2] += at2 * e5lo(vd[d]);
        va[d * 2 + 1] += at2 * e5hi(vd[d]);
      }
    }
    alignas(16) unsigned od[8];
#pragma unroll
    for (int p = 0; p < 8; ++p) {
      unsigned a = __builtin_bit_cast(unsigned, va[p * 2]) + 0x00800080u;
      unsigned b = __builtin_bit_cast(unsigned, va[p * 2 + 1]) + 0x00800080u;
      od[p] = __builtin_amdgcn_perm(b, a, 0x07050301u);
    }
    u8* dp = wv + (size_t)(e0 + ii) * 256 + hh * 32;
    *(uint4*)dp = *(const uint4*)&od[0];
    *(uint4*)(dp + 16) = *(const uint4*)&od[4];
  }
}

// ---------------- node gather-mean + x1/X1cat build (wv in dst-sorted order) ------------
__global__ __launch_bounds__(256) void node_gather(const unsigned* __restrict__ off,
                                                   const unsigned* __restrict__ cnt,
                                                   const u8* __restrict__ wv,
                                                   const float* __restrict__ x,
                                                   float* __restrict__ x1,
                                                   u16* __restrict__ X1cat) {
  int n = blockIdx.x * 4 + (threadIdx.x >> 6);
  int lane = threadIdx.x & 63;
  unsigned st = off[n], c = cnt[n];
  float a0 = 0.f, a1 = 0.f, a2 = 0.f, a3 = 0.f;
  for (unsigned j = 0; j < c; ++j) {
    unsigned d = *(const unsigned*)(wv + (size_t)(st + j) * 256 + lane * 4);
    float f[4];
    dec4(d, f);
    a0 += f[0]; a1 += f[1]; a2 += f[2]; a3 += f[3];
  }
  float inv = 1.0f / fmaxf((float)c, 1.0f);
  float4 xv = *(const float4*)(x + (size_t)n * 256 + lane * 4);
  float4 x1v = {xv.x + a0 * inv, xv.y + a1 * inv, xv.z + a2 * inv, xv.w + a3 * inv};
  *(float4*)(x1 + (size_t)n * 256 + lane * 4) = x1v;
  ushort4 a, bq;
  a.x = f2h(x1v.x); a.y = f2h(x1v.y); a.z = f2h(x1v.z); a.w = f2h(x1v.w);
  bq.x = f2h(xv.x); bq.y = f2h(xv.y); bq.z = f2h(xv.z); bq.w = f2h(xv.w);
  *(ushort4*)(X1cat + (size_t)n * 512 + lane * 4) = a;
  *(ushort4*)(X1cat + (size_t)n * 512 + 256 + lane * 4) = bq;
}

extern "C" void kernel_launch(void* const* d_in, const int* in_sizes, int n_in,
                              void* d_out, int out_size, void* d_ws, size_t ws_size,
                              hipStream_t stream) {
  const float* x = (const float*)d_in[0];
  const int* eidx = (const int*)d_in[1];
  const float* eattr = (const float*)d_in[2];
  const float* qW1 = (const float*)d_in[3];
  const float* qb1 = (const float*)d_in[4];
  const float* qW2 = (const float*)d_in[5];
  const float* qb2 = (const float*)d_in[6];
  const float* kW1 = (const float*)d_in[7];
  const float* kb1 = (const float*)d_in[8];
  const float* kW2 = (const float*)d_in[9];
  const float* kb2 = (const float*)d_in[10];
  const float* vW1 = (const float*)d_in[11];
  const float* vb1 = (const float*)d_in[12];
  const float* vW2 = (const float*)d_in[13];
  const float* vb2 = (const float*)d_in[14];
  const float* sW1 = (const float*)d_in[15];
  const float* sb1 = (const float*)d_in[16];
  const float* sW2 = (const float*)d_in[17];
  const float* sb2 = (const float*)d_in[18];
  const float* fW1 = (const float*)d_in[19];
  const float* fb1 = (const float*)d_in[20];
  const float* fW2 = (const float*)d_in[21];
  const float* fb2 = (const float*)d_in[22];
  const float* lng = (const float*)d_in[23];
  const float* lnb = (const float*)d_in[24];
  const float* rW = (const float*)d_in[25];
  const float* rb = (const float*)d_in[26];

  const size_t N = N_NODES;
  char* ws = (char*)d_ws;
  size_t off_b = 0;
  auto alloc = [&](size_t bytes) {
    void* p = ws + off_b;
    off_b = (off_b + bytes + 255) & ~(size_t)255;
    return p;
  };
  u16* W1catT = (u16*)alloc((size_t)3072 * 256 * 2);
  u16* W2T = (u16*)alloc((size_t)768 * 512 * 2);
  u16* rWT = (u16*)alloc((size_t)256 * 512 * 2);
  u16* fW1T = (u16*)alloc((size_t)512 * 256 * 2);
  u16* fW2T = (u16*)alloc((size_t)256 * 512 * 2);
  u16* w1e16 = (u16*)alloc((size_t)9 * 512 * 2);
  float* b1cat = (float*)alloc((size_t)1536 * 4);
  unsigned* cnt = (unsigned*)alloc(N * 4);
  unsigned* offs = (unsigned*)alloc(N * 4);
  unsigned* woff = (unsigned*)alloc(N * 4);
  unsigned* eid = (unsigned*)alloc((size_t)N_EDGES * 4);
  float* biasb = (float*)alloc((size_t)N_EDGES * 8 * 4);  // 8.4 MB s-MLP bias
  u8* AB = (u8*)alloc(N * 3072);  // e5m2, 201 MB; node-stage aliases below
  // xn (fp16 LN output, 33.5 MB) and wv (fp8 per-edge, 67 MB) both live in d_out;
  // xn is dead before qkv_attn writes wv.
  u16* xn = (u16*)d_out;
  u8* wv = (u8*)d_out;
  float* x1 = (float*)AB;                        // 64 MB
  u16* X1cat = (u16*)(AB + (size_t)67108864);    // 64 MB
  float* x2 = (float*)(AB + (size_t)134217728);  // 64 MB
  u16* xn2 = (u16*)AB;                           // 32 MB (x1 dead)
  u16* Hf = (u16*)(AB + (size_t)33554432);       // 64 MB (X1cat dead)

  hipMemsetAsync(cnt, 0, N * 4, stream);
  hist_kernel<<<N_EDGES / 256, 256, 0, stream>>>(eidx + N_EDGES, cnt);
  scan_kernel<<<1, 1024, 0, stream>>>(cnt, offs, woff);
  scatter_ids<<<N_EDGES / 256, 256, 0, stream>>>(eidx + N_EDGES, woff, eid);
  prep_w1catT<<<3072, 256, 0, stream>>>(W1catT, qW1, kW1, vW1);
  prep_w2T<<<768, 256, 0, stream>>>(W2T, qW2, kW2, vW2);
  prep_w1e16<<<9, 512, 0, stream>>>(w1e16, qW1, kW1, vW1);
  prep_b1cat<<<6, 256, 0, stream>>>(b1cat, qb1, kb1, vb1);
  transpose_cast<<<256, 256, 0, stream>>>(rWT, rW, 512, 256);
  transpose_cast<<<512, 256, 0, stream>>>(fW1T, fW1, 256, 512);
  transpose_cast<<<256, 256, 0, stream>>>(fW2T, fW2, 512, 256);
  bias_kernel<<<N_EDGES / 256, 256, 0, stream>>>(eattr, sW1, sb1, sW2, sb2, biasb);

  ln_kernel<<<N_NODES / 4, 256, 0, stream>>>(x, lng, lnb, xn);
  gemm2_ab<<<12288, 256, 0, stream>>>(xn, W1catT, b1cat, AB);
  qkv_attn<<<N_EDGES / 64, 256, 0, stream>>>(eidx, eattr, eid, AB, W2T, w1e16,
                                             qb2, kb2, vb2, biasb, wv);
  node_gather<<<N_NODES / 4, 256, 0, stream>>>(offs, cnt, wv, x, x1, X1cat);
  gemm_bt<<<dim3(N_NODES / 128, 2), 256, 0, stream>>>(X1cat, rWT, 512, EpiX2{x2, x1, rb});
  ln_kernel<<<N_NODES / 4, 256, 0, stream>>>(x2, lng, lnb, xn2);
  gemm_bt<<<dim3(N_NODES / 128, 4), 256, 0, stream>>>(xn2, fW1T, 256, EpiHf{Hf, fb1});
  gemm_bt<<<dim3(N_NODES / 128, 2), 256, 0, stream>>>(Hf, fW2T, 512, EpiOut{(float*)d_out, fb2, x2});
}

// Round 5
// 2305.262 us; speedup vs baseline: 1.1932x; 1.1932x over previous
//
#include <hip/hip_runtime.h>

#define N_NODES 65536
#define N_EDGES 262144

typedef unsigned short u16;
typedef unsigned char u8;
typedef float f32x4 __attribute__((ext_vector_type(4)));
typedef _Float16 h2 __attribute__((ext_vector_type(2)));
typedef _Float16 v8h __attribute__((ext_vector_type(8)));

__device__ __forceinline__ u16 f2h(float f) {
  return __builtin_bit_cast(u16, (_Float16)f);
}
// 8-bit e5m2 == top byte of fp16 with RNE rounding.
__device__ __forceinline__ u8 f2e5m2(float f) {
  _Float16 h = (_Float16)f;
  u16 hb = __builtin_bit_cast(u16, h);
  hb = (u16)(hb + 0x7F + ((hb >> 8) & 1));
  return (u8)(hb >> 8);
}
// decode dword = 4 e5m2 bytes -> 4 floats (node_gather)
__device__ __forceinline__ void dec4(unsigned d, float* o) {
  o[0] = (float)__builtin_bit_cast(_Float16, (u16)((d << 8) & 0xFF00u));
  o[1] = (float)__builtin_bit_cast(_Float16, (u16)(d & 0xFF00u));
  o[2] = (float)__builtin_bit_cast(_Float16, (u16)((d >> 8) & 0xFF00u));
  o[3] = (float)__builtin_bit_cast(_Float16, (u16)((d >> 16) & 0xFF00u));
}
// e5m2 bytes (b0,b1) of dword -> fp16 pair via one v_perm
__device__ __forceinline__ h2 e5lo(unsigned d) {
  return __builtin_bit_cast(h2, __builtin_amdgcn_perm(d, 0u, 0x05000400u));
}
__device__ __forceinline__ h2 e5hi(unsigned d) {
  return __builtin_bit_cast(h2, __builtin_amdgcn_perm(d, 0u, 0x07000600u));
}
// sigmoid-form gelu: x - x/(1+exp(1.702x)); ~6 VALU ops
__device__ __forceinline__ float gelu_s(float x) {
  float e = __expf(1.702f * x);
  return x - __fdividef(x, e + 1.0f);
}
// tanh-form gelu (node f-MLP epilogue)
__device__ __forceinline__ float gelu_f(float x) {
  float y = 1.5957691216057308f * (x + 0.044715f * x * x * x);
  float e = __expf(y);
  return x - __fdividef(x, e + 1.0f);
}
// async global->LDS, 16 bytes per lane; LDS dest is wave-uniform base + lane*16
__device__ __forceinline__ void gld16(const u16* g, u16* l) {
  __builtin_amdgcn_global_load_lds(
      (const __attribute__((address_space(1))) void*)g,
      (__attribute__((address_space(3))) void*)l, 16, 0, 0);
}

// ---------------- LayerNorm -> fp16 ----------------
__global__ __launch_bounds__(256) void ln_kernel(const float* __restrict__ x,
                                                 const float* __restrict__ g,
                                                 const float* __restrict__ b,
                                                 u16* __restrict__ out) {
  int row = blockIdx.x * 4 + (threadIdx.x >> 6);
  int lane = threadIdx.x & 63;
  float4 v = ((const float4*)(x + (size_t)row * 256))[lane];
  float s = v.x + v.y + v.z + v.w;
  float s2 = v.x * v.x + v.y * v.y + v.z * v.z + v.w * v.w;
#pragma unroll
  for (int off = 1; off < 64; off <<= 1) {
    s += __shfl_xor(s, off, 64);
    s2 += __shfl_xor(s2, off, 64);
  }
  float mean = s * (1.0f / 256.0f);
  float var = s2 * (1.0f / 256.0f) - mean * mean;
  float rs = rsqrtf(var + 1e-5f);
  float4 gv = ((const float4*)g)[lane];
  float4 bv = ((const float4*)b)[lane];
  ushort4 o;
  o.x = f2h((v.x - mean) * rs * gv.x + bv.x);
  o.y = f2h((v.y - mean) * rs * gv.y + bv.y);
  o.z = f2h((v.z - mean) * rs * gv.z + bv.z);
  o.w = f2h((v.w - mean) * rs * gv.w + bv.w);
  *(ushort4*)(out + (size_t)row * 256 + lane * 4) = o;
}

// ---------------- generic fp16 GEMM (round-0 gemm_bt: best measured for small node GEMMs)
template <typename Epi>
__global__ __launch_bounds__(256) void gemm_bt(const u16* __restrict__ A,
                                               const u16* __restrict__ BT,
                                               int K, Epi epi) {
  __shared__ __align__(16) u16 sA[128 * 48];
  __shared__ __align__(16) u16 sB[128 * 48];
  const int tm = blockIdx.x * 128, tn = blockIdx.y * 128;
  const int t = threadIdx.x;
  const int wave = t >> 6, lane = t & 63;
  const int lrow = lane & 15, quad = lane >> 4;
  const int wrow = (wave & 1) * 64, wcol = (wave >> 1) * 64;
  const int r = t >> 2, c = (t & 3) << 3;
  f32x4 acc[4][4];
  const f32x4 z = {0.f, 0.f, 0.f, 0.f};
#pragma unroll
  for (int i = 0; i < 4; ++i)
#pragma unroll
    for (int j = 0; j < 4; ++j) acc[i][j] = z;
  for (int k0 = 0; k0 < K; k0 += 32) {
    *(uint4*)&sA[r * 48 + c] = *(const uint4*)&A[(size_t)(tm + r) * K + k0 + c];
    *(uint4*)&sA[(r + 64) * 48 + c] = *(const uint4*)&A[(size_t)(tm + r + 64) * K + k0 + c];
    *(uint4*)&sB[r * 48 + c] = *(const uint4*)&BT[(size_t)(tn + r) * K + k0 + c];
    *(uint4*)&sB[(r + 64) * 48 + c] = *(const uint4*)&BT[(size_t)(tn + r + 64) * K + k0 + c];
    __syncthreads();
    v8h af[4], bfv[4];
#pragma unroll
    for (int i = 0; i < 4; ++i) af[i] = *(const v8h*)&sA[(wrow + i * 16 + lrow) * 48 + quad * 8];
#pragma unroll
    for (int j = 0; j < 4; ++j) bfv[j] = *(const v8h*)&sB[(wcol + j * 16 + lrow) * 48 + quad * 8];
#pragma unroll
    for (int i = 0; i < 4; ++i)
#pragma unroll
      for (int j = 0; j < 4; ++j)
        acc[i][j] = __builtin_amdgcn_mfma_f32_16x16x32_f16(af[i], bfv[j], acc[i][j], 0, 0, 0);
    __syncthreads();
  }
#pragma unroll
  for (int i = 0; i < 4; ++i)
#pragma unroll
    for (int j = 0; j < 4; ++j)
#pragma unroll
      for (int rg = 0; rg < 4; ++rg)
        epi(tm + wrow + i * 16 + quad * 4 + rg, tn + wcol + j * 16 + lrow, acc[i][j][rg]);
}

// ---------------- AB GEMM core (128x128 tile, BK=32, double-buffered gload_lds) --------
#define GEMM_DBUF(K_)                                                                    \
  const int t = threadIdx.x;                                                             \
  const int wave = t >> 6, lane = t & 63;                                                \
  const int lrow = lane & 15, quad = lane >> 4;                                          \
  const int wrow = (wave & 1) * 64, wcol = (wave >> 1) * 64;                             \
  const int sa0 = 2 * wave, sa1 = 2 * wave + 1;                                          \
  const u16* pa0 = A + (size_t)(tm + sa0 * 16 + lrow) * (K_) + quad * 8;                 \
  const u16* pa1 = A + (size_t)(tm + sa1 * 16 + lrow) * (K_) + quad * 8;                 \
  const u16* pb0 = BT + (size_t)(tn + sa0 * 16 + lrow) * (K_) + quad * 8;                \
  const u16* pb1 = BT + (size_t)(tn + sa1 * 16 + lrow) * (K_) + quad * 8;                \
  f32x4 acc[4][4];                                                                       \
  {                                                                                      \
    const f32x4 z = {0.f, 0.f, 0.f, 0.f};                                                \
    _Pragma("unroll") for (int i = 0; i < 4; ++i)                                        \
        _Pragma("unroll") for (int j = 0; j < 4; ++j) acc[i][j] = z;                     \
  }                                                                                      \
  gld16(pa0, &sAB[sa0 * 512]);                                                           \
  gld16(pa1, &sAB[sa1 * 512]);                                                           \
  gld16(pb0, &sAB[4096 + sa0 * 512]);                                                    \
  gld16(pb1, &sAB[4096 + sa1 * 512]);                                                    \
  pa0 += 32; pa1 += 32; pb0 += 32; pb1 += 32;                                            \
  __syncthreads();                                                                       \
  int cur = 0;                                                                           \
  _Pragma("unroll") for (int k0 = 32; k0 < (K_); k0 += 32) {                             \
    const int nxt = cur ^ 1;                                                             \
    gld16(pa0, &sAB[nxt * 8192 + sa0 * 512]);                                            \
    gld16(pa1, &sAB[nxt * 8192 + sa1 * 512]);                                            \
    gld16(pb0, &sAB[nxt * 8192 + 4096 + sa0 * 512]);                                     \
    gld16(pb1, &sAB[nxt * 8192 + 4096 + sa1 * 512]);                                     \
    pa0 += 32; pa1 += 32; pb0 += 32; pb1 += 32;                                          \
    v8h af[4], bfv[4];                                                                   \
    _Pragma("unroll") for (int i = 0; i < 4; ++i) af[i] =                                \
        *(const v8h*)&sAB[cur * 8192 + ((wave & 1) * 4 + i) * 512 + lane * 8];           \
    _Pragma("unroll") for (int j = 0; j < 4; ++j) bfv[j] =                               \
        *(const v8h*)&sAB[cur * 8192 + 4096 + ((wave >> 1) * 4 + j) * 512 + lane * 8];   \
    _Pragma("unroll") for (int i = 0; i < 4; ++i)                                        \
        _Pragma("unroll") for (int j = 0; j < 4; ++j) acc[i][j] =                        \
            __builtin_amdgcn_mfma_f32_16x16x32_f16(af[i], bfv[j], acc[i][j], 0, 0, 0);   \
    __syncthreads();                                                                     \
    cur = nxt;                                                                           \
  }                                                                                      \
  {                                                                                      \
    v8h af[4], bfv[4];                                                                   \
    _Pragma("unroll") for (int i = 0; i < 4; ++i) af[i] =                                \
        *(const v8h*)&sAB[cur * 8192 + ((wave & 1) * 4 + i) * 512 + lane * 8];           \
    _Pragma("unroll") for (int j = 0; j < 4; ++j) bfv[j] =                               \
        *(const v8h*)&sAB[cur * 8192 + 4096 + ((wave >> 1) * 4 + j) * 512 + lane * 8];   \
    _Pragma("unroll") for (int i = 0; i < 4; ++i)                                        \
        _Pragma("unroll") for (int j = 0; j < 4; ++j) acc[i][j] =                        \
            __builtin_amdgcn_mfma_f32_16x16x32_f16(af[i], bfv[j], acc[i][j], 0, 0, 0);   \
  }

// specialized AB GEMM: M=65536, N=3072, K=256; e5m2 byte output staged through LDS
// (stride 136 -> quads land in disjoint bank groups), XCD-chunked swizzle.
__global__ __launch_bounds__(256) void gemm2_ab(const u16* __restrict__ A,
                                                const u16* __restrict__ BT,
                                                const float* __restrict__ b1cat,
                                                u8* __restrict__ out) {
  __shared__ __align__(16) u16 sAB[16384];
  const int bid = blockIdx.x;  // 12288 = 8 xcd * 64 mt * 24 nt
  const int local = bid >> 3;
  const int mt = (bid & 7) * 64 + local / 24;
  const int nt = local % 24;
  const int tm = mt * 128, tn = nt * 128;
  GEMM_DBUF(256)
  __syncthreads();  // last-tile LDS reads must drain before sAB reuse
  float bj[4];
#pragma unroll
  for (int j = 0; j < 4; ++j)
    bj[j] = (nt < 12) ? b1cat[tn + wcol + j * 16 + lrow] : 0.f;
  u8* sb = (u8*)sAB;
#pragma unroll
  for (int i = 0; i < 4; ++i)
#pragma unroll
    for (int j = 0; j < 4; ++j)
#pragma unroll
      for (int rg = 0; rg < 4; ++rg)
        sb[(wrow + i * 16 + quad * 4 + rg) * 136 + wcol + j * 16 + lrow] =
            f2e5m2(acc[i][j][rg] + bj[j]);
  __syncthreads();
  {
    int ir = t >> 1, sg = t & 1;
    const u8* srcp = &sb[ir * 136 + sg * 64];
    uint2* dstp = (uint2*)(out + (size_t)(tm + ir) * 3072 + tn + sg * 64);
#pragma unroll
    for (int q = 0; q < 8; ++q) dstp[q] = *(const uint2*)(srcp + q * 8);
  }
}

struct EpiX2 {
  float* x2;
  const float* x1;
  const float* rb;
  __device__ void operator()(int m, int n, float v) const {
    x2[(size_t)m * 256 + n] = v + rb[n] + x1[(size_t)m * 256 + n];
  }
};
struct EpiHf {
  u16* hf;
  const float* b1;
  __device__ void operator()(int m, int n, float v) const {
    hf[(size_t)m * 512 + n] = f2h(gelu_f(v + b1[n]));
  }
};
struct EpiOut {
  float* out;
  const float* b2;
  const float* x2;
  __device__ void operator()(int m, int n, float v) const {
    out[(size_t)m * 256 + n] = v + b2[n] + x2[(size_t)m * 256 + n];
  }
};

// ---------------- weight repacks ----------------
__global__ void prep_w1catT(u16* __restrict__ out, const float* __restrict__ qW1,
                            const float* __restrict__ kW1, const float* __restrict__ vW1) {
  int cIdx = blockIdx.x;
  int rIdx = threadIdx.x;
  int sec = cIdx >> 9;
  int h = cIdx & 511;
  int mlp = sec % 3;
  const float* W1 = (mlp == 0) ? qW1 : (mlp == 1) ? kW1 : vW1;
  int rowoff = (sec < 3) ? 0 : 256;
  out[(size_t)cIdx * 256 + rIdx] = f2h(W1[(size_t)(rowoff + rIdx) * 512 + h]);
}
__global__ void prep_w2T(u16* __restrict__ out, const float* __restrict__ qW2,
                         const float* __restrict__ kW2, const float* __restrict__ vW2) {
  int row = blockIdx.x;
  int m = row >> 8, n = row & 255;
  const float* W2 = (m == 0) ? qW2 : (m == 1) ? kW2 : vW2;
  for (int k = threadIdx.x; k < 512; k += 256)
    out[(size_t)row * 512 + k] = f2h(W2[(size_t)k * 256 + n]);
}
__global__ void transpose_cast(u16* __restrict__ out, const float* __restrict__ in, int K, int Nn) {
  int n = blockIdx.x;
  for (int k = threadIdx.x; k < K; k += blockDim.x)
    out[(size_t)n * K + k] = f2h(in[(size_t)k * Nn + n]);
}
__global__ void prep_w1e16(u16* __restrict__ out, const float* __restrict__ qW1,
                           const float* __restrict__ kW1, const float* __restrict__ vW1) {
  int b = blockIdx.x;  // m*3 + r
  int m = b / 3, r = b % 3;
  const float* W1 = (m == 0) ? qW1 : (m == 1) ? kW1 : vW1;
  out[(size_t)b * 512 + threadIdx.x] = f2h(W1[(size_t)(512 + r) * 512 + threadIdx.x]);
}
__global__ void prep_b1cat(float* __restrict__ out, const float* __restrict__ qb1,
                           const float* __restrict__ kb1, const float* __restrict__ vb1) {
  int idx = blockIdx.x * 256 + threadIdx.x;  // 1536
  const float* b = (idx < 512) ? qb1 : (idx < 1024) ? kb1 : vb1;
  out[idx] = b[idx & 511];
}

// ---------------- s-MLP bias precompute: bias[e][h], one thread per edge ----------------
__global__ __launch_bounds__(256) void bias_kernel(const float* __restrict__ eattr,
                                                   const float* __restrict__ sW1,
                                                   const float* __restrict__ sb1,
                                                   const float* __restrict__ sW2,
                                                   const float* __restrict__ sb2,
                                                   float* __restrict__ biasb) {
  int e = blockIdx.x * 256 + threadIdx.x;
  const float* ea = eattr + (size_t)e * 7;
  float a0 = ea[3], a1 = ea[4], a2 = ea[5], a3 = ea[6];
  float acc[8];
#pragma unroll
  for (int h = 0; h < 8; ++h) acc[h] = sb2[h];
#pragma unroll 4
  for (int j = 0; j < 64; ++j) {
    float zz = fmaxf(a0 * sW1[j] + a1 * sW1[64 + j] + a2 * sW1[128 + j] + a3 * sW1[192 + j] + sb1[j], 0.f);
#pragma unroll
    for (int h = 0; h < 8; ++h) acc[h] += zz * sW2[j * 8 + h];
  }
  float4* bp = (float4*)(biasb + (size_t)e * 8);
  float4 v0 = {acc[0], acc[1], acc[2], acc[3]};
  float4 v1 = {acc[4], acc[5], acc[6], acc[7]};
  bp[0] = v0;
  bp[1] = v1;
}

// ---------------- CSR build ----------------
__global__ __launch_bounds__(256) void hist_kernel(const int* __restrict__ dst,
                                                   unsigned* __restrict__ cnt) {
  int e = blockIdx.x * 256 + threadIdx.x;
  atomicAdd(&cnt[dst[e]], 1u);
}
__global__ __launch_bounds__(1024) void scan_kernel(const unsigned* __restrict__ cnt,
                                                    unsigned* __restrict__ off,
                                                    unsigned* __restrict__ woff) {
  __shared__ unsigned s_part[1024];
  int t = threadIdx.x;
  unsigned local[64];
  unsigned run = 0;
  const uint4* cp = (const uint4*)(cnt + t * 64);
#pragma unroll
  for (int j = 0; j < 16; ++j) {
    uint4 v = cp[j];
    local[j * 4 + 0] = v.x; local[j * 4 + 1] = v.y;
    local[j * 4 + 2] = v.z; local[j * 4 + 3] = v.w;
  }
#pragma unroll
  for (int j = 0; j < 64; ++j) { unsigned c = local[j]; local[j] = run; run += c; }
  s_part[t] = run;
  __syncthreads();
  for (int d = 1; d < 1024; d <<= 1) {
    unsigned v = (t >= d) ? s_part[t - d] : 0u;
    __syncthreads();
    s_part[t] += v;
    __syncthreads();
  }
  unsigned base = (t == 0) ? 0u : s_part[t - 1];
  for (int j = 0; j < 64; ++j) {
    unsigned o = base + local[j];
    off[t * 64 + j] = o;
    woff[t * 64 + j] = o;
  }
}
__global__ __launch_bounds__(256) void scatter_ids(const int* __restrict__ dst,
                                                   unsigned* __restrict__ woff,
                                                   unsigned* __restrict__ eid) {
  int e = blockIdx.x * 256 + threadIdx.x;
  unsigned pos = atomicAdd(&woff[dst[e]], 1u);
  eid[pos] = (unsigned)e;
}

// ---------------- fused QKV GEMM + attention: 32 edges/block (dst-sorted) ----------------
// 32-edge tiles: LDS ~35 KB -> 4 blocks/CU (16 waves, 2x round-3 TLP). 8 assemble segs
// of 16 cols (one 16B src + one 16B dst load per thread per chunk). acc[1][8] per wave
// (32 VGPR) + __launch_bounds__(256,4) keeps VGPR <= 128 so occupancy is LDS-capped.
__global__ __launch_bounds__(256, 4) void qkv_attn(
    const int* __restrict__ eidx, const float* __restrict__ eattr,
    const unsigned* __restrict__ eid,
    const u8* __restrict__ AB, const u16* __restrict__ W2T, const u16* __restrict__ w1e16,
    const float* __restrict__ qb2, const float* __restrict__ kb2, const float* __restrict__ vb2,
    const float* __restrict__ biasb, u8* __restrict__ wv) {
  __shared__ __align__(16) u8 sQ[32][784];  // e5m2 q|k|v per edge, stride 784
  __shared__ __align__(16) u8 sRaw[8704];   // sH[32][136] u16 (GEMM) / sS[32][8][8] f32 (attn)
  __shared__ int s_src[32], s_dst[32];
  __shared__ unsigned s_eid[32];
  __shared__ __align__(16) float s_ea[32][4];
  u16(*sH)[136] = (u16(*)[136])sRaw;
  float(*sS)[8][8] = (float(*)[8][8])sRaw;
  const int t = threadIdx.x;
  const int e0 = blockIdx.x * 32;
  if (t < 32) {
    unsigned e = eid[e0 + t];
    s_eid[t] = e;
    s_src[t] = eidx[e];
    s_dst[t] = eidx[N_EDGES + e];
    const float* ea = eattr + (size_t)e * 7;
    s_ea[t][0] = ea[0]; s_ea[t][1] = ea[1]; s_ea[t][2] = ea[2];
  }
  __syncthreads();
  const int i = t & 31, seg = t >> 5;  // 32 edges x 8 segs of 16 cols
  const int lane = t & 63, wave = t >> 6;
  const int lrow = lane & 15, quad = lane >> 4;
  const int wrow = (wave & 1) * 16, wcol = (wave >> 1) * 128;
  h2 ea0h, ea1h, ea2h;
  ea0h[0] = ea0h[1] = (_Float16)s_ea[i][0];
  ea1h[0] = ea1h[1] = (_Float16)s_ea[i][1];
  ea2h[0] = ea2h[1] = (_Float16)s_ea[i][2];
  const u8* ABs = AB + (size_t)s_src[i] * 3072 + seg * 16;
  const u8* ABd = AB + (size_t)s_dst[i] * 3072 + 1536 + seg * 16;
#pragma unroll 1
  for (int m = 0; m < 3; ++m) {
    const unsigned* w32 = (const unsigned*)(w1e16 + (size_t)m * 1536);
    const u8* rsB = ABs + m * 512;
    const u8* rdB = ABd + m * 512;
    const u16* Wm = W2T + (size_t)(m * 256 + wcol) * 512;
    f32x4 acc[8];
    {
      const f32x4 z = {0.f, 0.f, 0.f, 0.f};
#pragma unroll
      for (int j = 0; j < 8; ++j) acc[j] = z;
    }
    for (int k0 = 0; k0 < 512; k0 += 128) {
      {  // assemble 16 cols per thread: edge i, cols [k0+seg*16, +16)
        alignas(16) unsigned sd[4], dd[4];
        *(uint4*)&sd[0] = *(const uint4*)(rsB + k0);
        *(uint4*)&dd[0] = *(const uint4*)(rdB + k0);
        const int cp0 = (k0 + seg * 16) >> 1;
        alignas(16) unsigned hout[8];
#pragma unroll
        for (int d = 0; d < 4; ++d) {
          int cp = cp0 + d * 2;
          h2 slo = e5lo(sd[d]) + e5lo(dd[d]);
          h2 shi = e5hi(sd[d]) + e5hi(dd[d]);
          slo += ea0h * __builtin_bit_cast(h2, w32[cp]);
          shi += ea0h * __builtin_bit_cast(h2, w32[cp + 1]);
          slo += ea1h * __builtin_bit_cast(h2, w32[256 + cp]);
          shi += ea1h * __builtin_bit_cast(h2, w32[256 + cp + 1]);
          slo += ea2h * __builtin_bit_cast(h2, w32[512 + cp]);
          shi += ea2h * __builtin_bit_cast(h2, w32[512 + cp + 1]);
          float g0 = gelu_s((float)slo[0]), g1 = gelu_s((float)slo[1]);
          float g2 = gelu_s((float)shi[0]), g3 = gelu_s((float)shi[1]);
          hout[d * 2] = (unsigned)f2h(g0) | ((unsigned)f2h(g1) << 16);
          hout[d * 2 + 1] = (unsigned)f2h(g2) | ((unsigned)f2h(g3) << 16);
        }
        uint4* hp = (uint4*)&sH[i][seg * 16];
        hp[0] = *(const uint4*)&hout[0];
        hp[1] = *(const uint4*)&hout[4];
      }
      __syncthreads();
#pragma unroll
      for (int ks = 0; ks < 4; ++ks) {
        int kk = ks * 32;
        v8h a0 = *(const v8h*)&sH[wrow + lrow][kk + quad * 8];
#pragma unroll
        for (int j = 0; j < 8; ++j) {
          v8h b = *(const v8h*)&Wm[(size_t)(j * 16 + lrow) * 512 + k0 + kk + quad * 8];
          acc[j] = __builtin_amdgcn_mfma_f32_16x16x32_f16(a0, b, acc[j], 0, 0, 0);
        }
      }
      __syncthreads();
    }
    // epilogue: +b2, e5m2-encode into sQ (this m's 256-byte slice)
    const float* b2 = (m == 0) ? qb2 : (m == 1) ? kb2 : vb2;
#pragma unroll
    for (int j = 0; j < 8; ++j)
#pragma unroll
      for (int rg = 0; rg < 4; ++rg) {
        int row = wrow + quad * 4 + rg;
        int col = wcol + j * 16 + lrow;
        sQ[row][m * 256 + col] = f2e5m2(acc[j][rg] + b2[col]);
      }
  }
  __syncthreads();  // sQ complete; sH dead -> sS aliases it
  // ---------------- attention phase: 256 threads = 32 edges x 8 heads ----------------
  const int hh = t & 7, ii = t >> 3;
  {
    alignas(16) unsigned qd[8];
    *(uint4*)&qd[0] = *(const uint4*)&sQ[ii][hh * 32];
    *(uint4*)&qd[4] = *(const uint4*)&sQ[ii][hh * 32 + 16];
    h2 qh[16];
#pragma unroll
    for (int d = 0; d < 8; ++d) { qh[d * 2] = e5lo(qd[d]); qh[d * 2 + 1] = e5hi(qd[d]); }
    float bias = biasb[(size_t)s_eid[ii] * 8 + hh];
    float sc[8];
#pragma unroll
    for (int g = 0; g < 8; ++g) {
      alignas(16) unsigned kd[8];
      *(uint4*)&kd[0] = *(const uint4*)&sQ[ii][256 + g * 32];
      *(uint4*)&kd[4] = *(const uint4*)&sQ[ii][256 + g * 32 + 16];
      h2 acc;
      acc[0] = acc[1] = (_Float16)0.f;
#pragma unroll
      for (int d = 0; d < 8; ++d) {
        acc += qh[d * 2] * e5lo(kd[d]);
        acc += qh[d * 2 + 1] * e5hi(kd[d]);
      }
      sc[g] = (float)acc[0] + (float)acc[1];
    }
#pragma unroll
    for (int g = 0; g < 8; ++g) sS[ii][hh][g] = sc[g] * 0.17677669529663687f + bias;
  }
  __syncthreads();
  {  // softmax over h (axis=1) per (edge, g=hh)
    const int g = hh;
    float mx = -1e30f;
#pragma unroll
    for (int h2i = 0; h2i < 8; ++h2i) mx = fmaxf(mx, sS[ii][h2i][g]);
    float ev[8], ssum = 0.f;
#pragma unroll
    for (int h2i = 0; h2i < 8; ++h2i) {
      ev[h2i] = __expf(sS[ii][h2i][g] - mx);
      ssum += ev[h2i];
    }
    float inv = 1.0f / ssum;
#pragma unroll
    for (int h2i = 0; h2i < 8; ++h2i) sS[ii][h2i][g] = ev[h2i] * inv;
  }
  __syncthreads();
  {  // wv[sorted pos][hh*32..] = sum_g attn[hh][g]*V[g][:]
    h2 va[16];
#pragma unroll
    for (int u = 0; u < 16; ++u) va[u][0] = va[u][1] = (_Float16)0.f;
#pragma unroll
    for (int g = 0; g < 8; ++g) {
      float at = sS[ii][hh][g];
      h2 at2;
      at2[0] = at2[1] = (_Float16)at;
      alignas(16) unsigned vd[8];
      *(uint4*)&vd[0] = *(const uint4*)&sQ[ii][512 + g * 32];
      *(uint4*)&vd[4] = *(const uint4*)&sQ[ii][512 + g * 32 + 16];
#pragma unroll
      for (int d = 0; d < 8; ++d) {
        va[d * 2] += at2 * e5lo(vd[d]);
        va[d * 2 + 1] += at2 * e5hi(vd[d]);
      }
    }
    alignas(16) unsigned od[8];
#pragma unroll
    for (int p = 0; p < 8; ++p) {
      unsigned a = __builtin_bit_cast(unsigned, va[p * 2]) + 0x00800080u;
      unsigned b = __builtin_bit_cast(unsigned, va[p * 2 + 1]) + 0x00800080u;
      od[p] = __builtin_amdgcn_perm(b, a, 0x07050301u);
    }
    u8* dp = wv + (size_t)(e0 + ii) * 256 + hh * 32;
    *(uint4*)dp = *(const uint4*)&od[0];
    *(uint4*)(dp + 16) = *(const uint4*)&od[4];
  }
}

// ---------------- node gather-mean + x1/X1cat build (wv in dst-sorted order) ------------
__global__ __launch_bounds__(256) void node_gather(const unsigned* __restrict__ off,
                                                   const unsigned* __restrict__ cnt,
                                                   const u8* __restrict__ wv,
                                                   const float* __restrict__ x,
                                                   float* __restrict__ x1,
                                                   u16* __restrict__ X1cat) {
  int n = blockIdx.x * 4 + (threadIdx.x >> 6);
  int lane = threadIdx.x & 63;
  unsigned st = off[n], c = cnt[n];
  float a0 = 0.f, a1 = 0.f, a2 = 0.f, a3 = 0.f;
  for (unsigned j = 0; j < c; ++j) {
    unsigned d = *(const unsigned*)(wv + (size_t)(st + j) * 256 + lane * 4);
    float f[4];
    dec4(d, f);
    a0 += f[0]; a1 += f[1]; a2 += f[2]; a3 += f[3];
  }
  float inv = 1.0f / fmaxf((float)c, 1.0f);
  float4 xv = *(const float4*)(x + (size_t)n * 256 + lane * 4);
  float4 x1v = {xv.x + a0 * inv, xv.y + a1 * inv, xv.z + a2 * inv, xv.w + a3 * inv};
  *(float4*)(x1 + (size_t)n * 256 + lane * 4) = x1v;
  ushort4 a, bq;
  a.x = f2h(x1v.x); a.y = f2h(x1v.y); a.z = f2h(x1v.z); a.w = f2h(x1v.w);
  bq.x = f2h(xv.x); bq.y = f2h(xv.y); bq.z = f2h(xv.z); bq.w = f2h(xv.w);
  *(ushort4*)(X1cat + (size_t)n * 512 + lane * 4) = a;
  *(ushort4*)(X1cat + (size_t)n * 512 + 256 + lane * 4) = bq;
}

extern "C" void kernel_launch(void* const* d_in, const int* in_sizes, int n_in,
                              void* d_out, int out_size, void* d_ws, size_t ws_size,
                              hipStream_t stream) {
  const float* x = (const float*)d_in[0];
  const int* eidx = (const int*)d_in[1];
  const float* eattr = (const float*)d_in[2];
  const float* qW1 = (const float*)d_in[3];
  const float* qb1 = (const float*)d_in[4];
  const float* qW2 = (const float*)d_in[5];
  const float* qb2 = (const float*)d_in[6];
  const float* kW1 = (const float*)d_in[7];
  const float* kb1 = (const float*)d_in[8];
  const float* kW2 = (const float*)d_in[9];
  const float* kb2 = (const float*)d_in[10];
  const float* vW1 = (const float*)d_in[11];
  const float* vb1 = (const float*)d_in[12];
  const float* vW2 = (const float*)d_in[13];
  const float* vb2 = (const float*)d_in[14];
  const float* sW1 = (const float*)d_in[15];
  const float* sb1 = (const float*)d_in[16];
  const float* sW2 = (const float*)d_in[17];
  const float* sb2 = (const float*)d_in[18];
  const float* fW1 = (const float*)d_in[19];
  const float* fb1 = (const float*)d_in[20];
  const float* fW2 = (const float*)d_in[21];
  const float* fb2 = (const float*)d_in[22];
  const float* lng = (const float*)d_in[23];
  const float* lnb = (const float*)d_in[24];
  const float* rW = (const float*)d_in[25];
  const float* rb = (const float*)d_in[26];

  const size_t N = N_NODES;
  char* ws = (char*)d_ws;
  size_t off_b = 0;
  auto alloc = [&](size_t bytes) {
    void* p = ws + off_b;
    off_b = (off_b + bytes + 255) & ~(size_t)255;
    return p;
  };
  u16* W1catT = (u16*)alloc((size_t)3072 * 256 * 2);
  u16* W2T = (u16*)alloc((size_t)768 * 512 * 2);
  u16* rWT = (u16*)alloc((size_t)256 * 512 * 2);
  u16* fW1T = (u16*)alloc((size_t)512 * 256 * 2);
  u16* fW2T = (u16*)alloc((size_t)256 * 512 * 2);
  u16* w1e16 = (u16*)alloc((size_t)9 * 512 * 2);
  float* b1cat = (float*)alloc((size_t)1536 * 4);
  unsigned* cnt = (unsigned*)alloc(N * 4);
  unsigned* offs = (unsigned*)alloc(N * 4);
  unsigned* woff = (unsigned*)alloc(N * 4);
  unsigned* eid = (unsigned*)alloc((size_t)N_EDGES * 4);
  float* biasb = (float*)alloc((size_t)N_EDGES * 8 * 4);  // 8.4 MB s-MLP bias
  u8* AB = (u8*)alloc(N * 3072);  // e5m2, 201 MB; node-stage aliases below
  // xn (fp16 LN output, 33.5 MB) and wv (fp8 per-edge, 67 MB) both live in d_out;
  // xn is dead before qkv_attn writes wv.
  u16* xn = (u16*)d_out;
  u8* wv = (u8*)d_out;
  float* x1 = (float*)AB;                        // 64 MB
  u16* X1cat = (u16*)(AB + (size_t)67108864);    // 64 MB
  float* x2 = (float*)(AB + (size_t)134217728);  // 64 MB
  u16* xn2 = (u16*)AB;                           // 32 MB (x1 dead)
  u16* Hf = (u16*)(AB + (size_t)33554432);       // 64 MB (X1cat dead)

  hipMemsetAsync(cnt, 0, N * 4, stream);
  hist_kernel<<<N_EDGES / 256, 256, 0, stream>>>(eidx + N_EDGES, cnt);
  scan_kernel<<<1, 1024, 0, stream>>>(cnt, offs, woff);
  scatter_ids<<<N_EDGES / 256, 256, 0, stream>>>(eidx + N_EDGES, woff, eid);
  prep_w1catT<<<3072, 256, 0, stream>>>(W1catT, qW1, kW1, vW1);
  prep_w2T<<<768, 256, 0, stream>>>(W2T, qW2, kW2, vW2);
  prep_w1e16<<<9, 512, 0, stream>>>(w1e16, qW1, kW1, vW1);
  prep_b1cat<<<6, 256, 0, stream>>>(b1cat, qb1, kb1, vb1);
  transpose_cast<<<256, 256, 0, stream>>>(rWT, rW, 512, 256);
  transpose_cast<<<512, 256, 0, stream>>>(fW1T, fW1, 256, 512);
  transpose_cast<<<256, 256, 0, stream>>>(fW2T, fW2, 512, 256);
  bias_kernel<<<N_EDGES / 256, 256, 0, stream>>>(eattr, sW1, sb1, sW2, sb2, biasb);

  ln_kernel<<<N_NODES / 4, 256, 0, stream>>>(x, lng, lnb, xn);
  gemm2_ab<<<12288, 256, 0, stream>>>(xn, W1catT, b1cat, AB);
  qkv_attn<<<N_EDGES / 32, 256, 0, stream>>>(eidx, eattr, eid, AB, W2T, w1e16,
                                             qb2, kb2, vb2, biasb, wv);
  node_gather<<<N_NODES / 4, 256, 0, stream>>>(offs, cnt, wv, x, x1, X1cat);
  gemm_bt<<<dim3(N_NODES / 128, 2), 256, 0, stream>>>(X1cat, rWT, 512, EpiX2{x2, x1, rb});
  ln_kernel<<<N_NODES / 4, 256, 0, stream>>>(x2, lng, lnb, xn2);
  gemm_bt<<<dim3(N_NODES / 128, 4), 256, 0, stream>>>(xn2, fW1T, 256, EpiHf{Hf, fb1});
  gemm_bt<<<dim3(N_NODES / 128, 2), 256, 0, stream>>>(Hf, fW2T, 512, EpiOut{(float*)d_out, fb2, x2});
}

// Round 6
// 1592.294 us; speedup vs baseline: 1.7274x; 1.4478x over previous
//
#include <hip/hip_runtime.h>

#define N_NODES 65536
#define N_EDGES 262144

typedef unsigned short u16;
typedef unsigned char u8;
typedef float f32x4 __attribute__((ext_vector_type(4)));
typedef _Float16 h2 __attribute__((ext_vector_type(2)));
typedef _Float16 v8h __attribute__((ext_vector_type(8)));

__device__ __forceinline__ u16 f2h(float f) {
  return __builtin_bit_cast(u16, (_Float16)f);
}
// 8-bit e5m2 == top byte of fp16 with RNE rounding.
__device__ __forceinline__ u8 f2e5m2(float f) {
  _Float16 h = (_Float16)f;
  u16 hb = __builtin_bit_cast(u16, h);
  hb = (u16)(hb + 0x7F + ((hb >> 8) & 1));
  return (u8)(hb >> 8);
}
// decode dword = 4 e5m2 bytes -> 4 floats (node_gather)
__device__ __forceinline__ void dec4(unsigned d, float* o) {
  o[0] = (float)__builtin_bit_cast(_Float16, (u16)((d << 8) & 0xFF00u));
  o[1] = (float)__builtin_bit_cast(_Float16, (u16)(d & 0xFF00u));
  o[2] = (float)__builtin_bit_cast(_Float16, (u16)((d >> 8) & 0xFF00u));
  o[3] = (float)__builtin_bit_cast(_Float16, (u16)((d >> 16) & 0xFF00u));
}
// e5m2 bytes (b0,b1) of dword -> fp16 pair via one v_perm
__device__ __forceinline__ h2 e5lo(unsigned d) {
  return __builtin_bit_cast(h2, __builtin_amdgcn_perm(d, 0u, 0x05000400u));
}
__device__ __forceinline__ h2 e5hi(unsigned d) {
  return __builtin_bit_cast(h2, __builtin_amdgcn_perm(d, 0u, 0x07000600u));
}
// sigmoid-form gelu: x - x/(1+exp(1.702x)); ~6 VALU ops
__device__ __forceinline__ float gelu_s(float x) {
  float e = __expf(1.702f * x);
  return x - __fdividef(x, e + 1.0f);
}
// tanh-form gelu (node f-MLP epilogue)
__device__ __forceinline__ float gelu_f(float x) {
  float y = 1.5957691216057308f * (x + 0.044715f * x * x * x);
  float e = __expf(y);
  return x - __fdividef(x, e + 1.0f);
}
// async global->LDS, 16 bytes per lane; LDS dest is wave-uniform base + lane*16
__device__ __forceinline__ void gld16(const u16* g, u16* l) {
  __builtin_amdgcn_global_load_lds(
      (const __attribute__((address_space(1))) void*)g,
      (__attribute__((address_space(3))) void*)l, 16, 0, 0);
}

// ---------------- LayerNorm -> fp16 ----------------
__global__ __launch_bounds__(256) void ln_kernel(const float* __restrict__ x,
                                                 const float* __restrict__ g,
                                                 const float* __restrict__ b,
                                                 u16* __restrict__ out) {
  int row = blockIdx.x * 4 + (threadIdx.x >> 6);
  int lane = threadIdx.x & 63;
  float4 v = ((const float4*)(x + (size_t)row * 256))[lane];
  float s = v.x + v.y + v.z + v.w;
  float s2 = v.x * v.x + v.y * v.y + v.z * v.z + v.w * v.w;
#pragma unroll
  for (int off = 1; off < 64; off <<= 1) {
    s += __shfl_xor(s, off, 64);
    s2 += __shfl_xor(s2, off, 64);
  }
  float mean = s * (1.0f / 256.0f);
  float var = s2 * (1.0f / 256.0f) - mean * mean;
  float rs = rsqrtf(var + 1e-5f);
  float4 gv = ((const float4*)g)[lane];
  float4 bv = ((const float4*)b)[lane];
  ushort4 o;
  o.x = f2h((v.x - mean) * rs * gv.x + bv.x);
  o.y = f2h((v.y - mean) * rs * gv.y + bv.y);
  o.z = f2h((v.z - mean) * rs * gv.z + bv.z);
  o.w = f2h((v.w - mean) * rs * gv.w + bv.w);
  *(ushort4*)(out + (size_t)row * 256 + lane * 4) = o;
}

// ---------------- generic fp16 GEMM (round-0 gemm_bt: best measured for small node GEMMs)
template <typename Epi>
__global__ __launch_bounds__(256) void gemm_bt(const u16* __restrict__ A,
                                               const u16* __restrict__ BT,
                                               int K, Epi epi) {
  __shared__ __align__(16) u16 sA[128 * 48];
  __shared__ __align__(16) u16 sB[128 * 48];
  const int tm = blockIdx.x * 128, tn = blockIdx.y * 128;
  const int t = threadIdx.x;
  const int wave = t >> 6, lane = t & 63;
  const int lrow = lane & 15, quad = lane >> 4;
  const int wrow = (wave & 1) * 64, wcol = (wave >> 1) * 64;
  const int r = t >> 2, c = (t & 3) << 3;
  f32x4 acc[4][4];
  const f32x4 z = {0.f, 0.f, 0.f, 0.f};
#pragma unroll
  for (int i = 0; i < 4; ++i)
#pragma unroll
    for (int j = 0; j < 4; ++j) acc[i][j] = z;
  for (int k0 = 0; k0 < K; k0 += 32) {
    *(uint4*)&sA[r * 48 + c] = *(const uint4*)&A[(size_t)(tm + r) * K + k0 + c];
    *(uint4*)&sA[(r + 64) * 48 + c] = *(const uint4*)&A[(size_t)(tm + r + 64) * K + k0 + c];
    *(uint4*)&sB[r * 48 + c] = *(const uint4*)&BT[(size_t)(tn + r) * K + k0 + c];
    *(uint4*)&sB[(r + 64) * 48 + c] = *(const uint4*)&BT[(size_t)(tn + r + 64) * K + k0 + c];
    __syncthreads();
    v8h af[4], bfv[4];
#pragma unroll
    for (int i = 0; i < 4; ++i) af[i] = *(const v8h*)&sA[(wrow + i * 16 + lrow) * 48 + quad * 8];
#pragma unroll
    for (int j = 0; j < 4; ++j) bfv[j] = *(const v8h*)&sB[(wcol + j * 16 + lrow) * 48 + quad * 8];
#pragma unroll
    for (int i = 0; i < 4; ++i)
#pragma unroll
      for (int j = 0; j < 4; ++j)
        acc[i][j] = __builtin_amdgcn_mfma_f32_16x16x32_f16(af[i], bfv[j], acc[i][j], 0, 0, 0);
    __syncthreads();
  }
#pragma unroll
  for (int i = 0; i < 4; ++i)
#pragma unroll
    for (int j = 0; j < 4; ++j)
#pragma unroll
      for (int rg = 0; rg < 4; ++rg)
        epi(tm + wrow + i * 16 + quad * 4 + rg, tn + wcol + j * 16 + lrow, acc[i][j][rg]);
}

// ---------------- AB GEMM core (128x128 tile, BK=32, double-buffered gload_lds) --------
#define GEMM_DBUF(K_)                                                                    \
  const int t = threadIdx.x;                                                             \
  const int wave = t >> 6, lane = t & 63;                                                \
  const int lrow = lane & 15, quad = lane >> 4;                                          \
  const int wrow = (wave & 1) * 64, wcol = (wave >> 1) * 64;                             \
  const int sa0 = 2 * wave, sa1 = 2 * wave + 1;                                          \
  const u16* pa0 = A + (size_t)(tm + sa0 * 16 + lrow) * (K_) + quad * 8;                 \
  const u16* pa1 = A + (size_t)(tm + sa1 * 16 + lrow) * (K_) + quad * 8;                 \
  const u16* pb0 = BT + (size_t)(tn + sa0 * 16 + lrow) * (K_) + quad * 8;                \
  const u16* pb1 = BT + (size_t)(tn + sa1 * 16 + lrow) * (K_) + quad * 8;                \
  f32x4 acc[4][4];                                                                       \
  {                                                                                      \
    const f32x4 z = {0.f, 0.f, 0.f, 0.f};                                                \
    _Pragma("unroll") for (int i = 0; i < 4; ++i)                                        \
        _Pragma("unroll") for (int j = 0; j < 4; ++j) acc[i][j] = z;                     \
  }                                                                                      \
  gld16(pa0, &sAB[sa0 * 512]);                                                           \
  gld16(pa1, &sAB[sa1 * 512]);                                                           \
  gld16(pb0, &sAB[4096 + sa0 * 512]);                                                    \
  gld16(pb1, &sAB[4096 + sa1 * 512]);                                                    \
  pa0 += 32; pa1 += 32; pb0 += 32; pb1 += 32;                                            \
  __syncthreads();                                                                       \
  int cur = 0;                                                                           \
  _Pragma("unroll") for (int k0 = 32; k0 < (K_); k0 += 32) {                             \
    const int nxt = cur ^ 1;                                                             \
    gld16(pa0, &sAB[nxt * 8192 + sa0 * 512]);                                            \
    gld16(pa1, &sAB[nxt * 8192 + sa1 * 512]);                                            \
    gld16(pb0, &sAB[nxt * 8192 + 4096 + sa0 * 512]);                                     \
    gld16(pb1, &sAB[nxt * 8192 + 4096 + sa1 * 512]);                                     \
    pa0 += 32; pa1 += 32; pb0 += 32; pb1 += 32;                                          \
    v8h af[4], bfv[4];                                                                   \
    _Pragma("unroll") for (int i = 0; i < 4; ++i) af[i] =                                \
        *(const v8h*)&sAB[cur * 8192 + ((wave & 1) * 4 + i) * 512 + lane * 8];           \
    _Pragma("unroll") for (int j = 0; j < 4; ++j) bfv[j] =                               \
        *(const v8h*)&sAB[cur * 8192 + 4096 + ((wave >> 1) * 4 + j) * 512 + lane * 8];   \
    _Pragma("unroll") for (int i = 0; i < 4; ++i)                                        \
        _Pragma("unroll") for (int j = 0; j < 4; ++j) acc[i][j] =                        \
            __builtin_amdgcn_mfma_f32_16x16x32_f16(af[i], bfv[j], acc[i][j], 0, 0, 0);   \
    __syncthreads();                                                                     \
    cur = nxt;                                                                           \
  }                                                                                      \
  {                                                                                      \
    v8h af[4], bfv[4];                                                                   \
    _Pragma("unroll") for (int i = 0; i < 4; ++i) af[i] =                                \
        *(const v8h*)&sAB[cur * 8192 + ((wave & 1) * 4 + i) * 512 + lane * 8];           \
    _Pragma("unroll") for (int j = 0; j < 4; ++j) bfv[j] =                               \
        *(const v8h*)&sAB[cur * 8192 + 4096 + ((wave >> 1) * 4 + j) * 512 + lane * 8];   \
    _Pragma("unroll") for (int i = 0; i < 4; ++i)                                        \
        _Pragma("unroll") for (int j = 0; j < 4; ++j) acc[i][j] =                        \
            __builtin_amdgcn_mfma_f32_16x16x32_f16(af[i], bfv[j], acc[i][j], 0, 0, 0);   \
  }

// specialized AB GEMM: M=65536, N=3072, K=256; e5m2 byte output staged through LDS
// (stride 136 -> quads land in disjoint bank groups), XCD-chunked swizzle.
__global__ __launch_bounds__(256) void gemm2_ab(const u16* __restrict__ A,
                                                const u16* __restrict__ BT,
                                                const float* __restrict__ b1cat,
                                                u8* __restrict__ out) {
  __shared__ __align__(16) u16 sAB[16384];
  const int bid = blockIdx.x;  // 12288 = 8 xcd * 64 mt * 24 nt
  const int local = bid >> 3;
  const int mt = (bid & 7) * 64 + local / 24;
  const int nt = local % 24;
  const int tm = mt * 128, tn = nt * 128;
  GEMM_DBUF(256)
  __syncthreads();  // last-tile LDS reads must drain before sAB reuse
  float bj[4];
#pragma unroll
  for (int j = 0; j < 4; ++j)
    bj[j] = (nt < 12) ? b1cat[tn + wcol + j * 16 + lrow] : 0.f;
  u8* sb = (u8*)sAB;
#pragma unroll
  for (int i = 0; i < 4; ++i)
#pragma unroll
    for (int j = 0; j < 4; ++j)
#pragma unroll
      for (int rg = 0; rg < 4; ++rg)
        sb[(wrow + i * 16 + quad * 4 + rg) * 136 + wcol + j * 16 + lrow] =
            f2e5m2(acc[i][j][rg] + bj[j]);
  __syncthreads();
  {
    int ir = t >> 1, sg = t & 1;
    const u8* srcp = &sb[ir * 136 + sg * 64];
    uint2* dstp = (uint2*)(out + (size_t)(tm + ir) * 3072 + tn + sg * 64);
#pragma unroll
    for (int q = 0; q < 8; ++q) dstp[q] = *(const uint2*)(srcp + q * 8);
  }
}

struct EpiX2 {
  float* x2;
  const float* x1;
  const float* rb;
  __device__ void operator()(int m, int n, float v) const {
    x2[(size_t)m * 256 + n] = v + rb[n] + x1[(size_t)m * 256 + n];
  }
};
struct EpiHf {
  u16* hf;
  const float* b1;
  __device__ void operator()(int m, int n, float v) const {
    hf[(size_t)m * 512 + n] = f2h(gelu_f(v + b1[n]));
  }
};
struct EpiOut {
  float* out;
  const float* b2;
  const float* x2;
  __device__ void operator()(int m, int n, float v) const {
    out[(size_t)m * 256 + n] = v + b2[n] + x2[(size_t)m * 256 + n];
  }
};

// ---------------- weight repacks ----------------
__global__ void prep_w1catT(u16* __restrict__ out, const float* __restrict__ qW1,
                            const float* __restrict__ kW1, const float* __restrict__ vW1) {
  int cIdx = blockIdx.x;
  int rIdx = threadIdx.x;
  int sec = cIdx >> 9;
  int h = cIdx & 511;
  int mlp = sec % 3;
  const float* W1 = (mlp == 0) ? qW1 : (mlp == 1) ? kW1 : vW1;
  int rowoff = (sec < 3) ? 0 : 256;
  out[(size_t)cIdx * 256 + rIdx] = f2h(W1[(size_t)(rowoff + rIdx) * 512 + h]);
}
__global__ void prep_w2T(u16* __restrict__ out, const float* __restrict__ qW2,
                         const float* __restrict__ kW2, const float* __restrict__ vW2) {
  int row = blockIdx.x;
  int m = row >> 8, n = row & 255;
  const float* W2 = (m == 0) ? qW2 : (m == 1) ? kW2 : vW2;
  for (int k = threadIdx.x; k < 512; k += 256)
    out[(size_t)row * 512 + k] = f2h(W2[(size_t)k * 256 + n]);
}
__global__ void transpose_cast(u16* __restrict__ out, const float* __restrict__ in, int K, int Nn) {
  int n = blockIdx.x;
  for (int k = threadIdx.x; k < K; k += blockDim.x)
    out[(size_t)n * K + k] = f2h(in[(size_t)k * Nn + n]);
}
__global__ void prep_w1e16(u16* __restrict__ out, const float* __restrict__ qW1,
                           const float* __restrict__ kW1, const float* __restrict__ vW1) {
  int b = blockIdx.x;  // m*3 + r
  int m = b / 3, r = b % 3;
  const float* W1 = (m == 0) ? qW1 : (m == 1) ? kW1 : vW1;
  out[(size_t)b * 512 + threadIdx.x] = f2h(W1[(size_t)(512 + r) * 512 + threadIdx.x]);
}
__global__ void prep_b1cat(float* __restrict__ out, const float* __restrict__ qb1,
                           const float* __restrict__ kb1, const float* __restrict__ vb1) {
  int idx = blockIdx.x * 256 + threadIdx.x;  // 1536
  const float* b = (idx < 512) ? qb1 : (idx < 1024) ? kb1 : vb1;
  out[idx] = b[idx & 511];
}

// ---------------- s-MLP bias precompute: bias[e][h], one thread per edge ----------------
__global__ __launch_bounds__(256) void bias_kernel(const float* __restrict__ eattr,
                                                   const float* __restrict__ sW1,
                                                   const float* __restrict__ sb1,
                                                   const float* __restrict__ sW2,
                                                   const float* __restrict__ sb2,
                                                   float* __restrict__ biasb) {
  int e = blockIdx.x * 256 + threadIdx.x;
  const float* ea = eattr + (size_t)e * 7;
  float a0 = ea[3], a1 = ea[4], a2 = ea[5], a3 = ea[6];
  float acc[8];
#pragma unroll
  for (int h = 0; h < 8; ++h) acc[h] = sb2[h];
#pragma unroll 4
  for (int j = 0; j < 64; ++j) {
    float zz = fmaxf(a0 * sW1[j] + a1 * sW1[64 + j] + a2 * sW1[128 + j] + a3 * sW1[192 + j] + sb1[j], 0.f);
#pragma unroll
    for (int h = 0; h < 8; ++h) acc[h] += zz * sW2[j * 8 + h];
  }
  float4* bp = (float4*)(biasb + (size_t)e * 8);
  float4 v0 = {acc[0], acc[1], acc[2], acc[3]};
  float4 v1 = {acc[4], acc[5], acc[6], acc[7]};
  bp[0] = v0;
  bp[1] = v1;
}

// ---------------- CSR build ----------------
__global__ __launch_bounds__(256) void hist_kernel(const int* __restrict__ dst,
                                                   unsigned* __restrict__ cnt) {
  int e = blockIdx.x * 256 + threadIdx.x;
  atomicAdd(&cnt[dst[e]], 1u);
}
__global__ __launch_bounds__(1024) void scan_kernel(const unsigned* __restrict__ cnt,
                                                    unsigned* __restrict__ off,
                                                    unsigned* __restrict__ woff) {
  __shared__ unsigned s_part[1024];
  int t = threadIdx.x;
  unsigned local[64];
  unsigned run = 0;
  const uint4* cp = (const uint4*)(cnt + t * 64);
#pragma unroll
  for (int j = 0; j < 16; ++j) {
    uint4 v = cp[j];
    local[j * 4 + 0] = v.x; local[j * 4 + 1] = v.y;
    local[j * 4 + 2] = v.z; local[j * 4 + 3] = v.w;
  }
#pragma unroll
  for (int j = 0; j < 64; ++j) { unsigned c = local[j]; local[j] = run; run += c; }
  s_part[t] = run;
  __syncthreads();
  for (int d = 1; d < 1024; d <<= 1) {
    unsigned v = (t >= d) ? s_part[t - d] : 0u;
    __syncthreads();
    s_part[t] += v;
    __syncthreads();
  }
  unsigned base = (t == 0) ? 0u : s_part[t - 1];
  for (int j = 0; j < 64; ++j) {
    unsigned o = base + local[j];
    off[t * 64 + j] = o;
    woff[t * 64 + j] = o;
  }
}
__global__ __launch_bounds__(256) void scatter_ids(const int* __restrict__ dst,
                                                   unsigned* __restrict__ woff,
                                                   unsigned* __restrict__ eid) {
  int e = blockIdx.x * 256 + threadIdx.x;
  unsigned pos = atomicAdd(&woff[dst[e]], 1u);
  eid[pos] = (unsigned)e;
}

// ---------------- fused QKV GEMM + attention: 32 edges/block (dst-sorted) ----------------
// 32-edge tiles, 34.8 KB LDS -> 4 blocks/CU (proven 48% occupancy, round 5).
// Fixes vs round 5: (a) wave col-slice 64 (acc[2][4], a0+a1) -> 2 MFMA per 16B W2T load,
// halving B-load issue; (b) rolled 1-deep register prefetch of next chunk's 2x16B gathers
// (+8 VGPR, NOT round 4's full unroll) so gather latency hides under assemble+MFMA.
__global__ __launch_bounds__(256, 4) void qkv_attn(
    const int* __restrict__ eidx, const float* __restrict__ eattr,
    const unsigned* __restrict__ eid,
    const u8* __restrict__ AB, const u16* __restrict__ W2T, const u16* __restrict__ w1e16,
    const float* __restrict__ qb2, const float* __restrict__ kb2, const float* __restrict__ vb2,
    const float* __restrict__ biasb, u8* __restrict__ wv) {
  __shared__ __align__(16) u8 sQ[32][784];  // e5m2 q|k|v per edge, stride 784
  __shared__ __align__(16) u8 sRaw[8704];   // sH[32][136] u16 (GEMM) / sS[32][8][8] f32 (attn)
  __shared__ int s_src[32], s_dst[32];
  __shared__ unsigned s_eid[32];
  __shared__ __align__(16) float s_ea[32][4];
  u16(*sH)[136] = (u16(*)[136])sRaw;
  float(*sS)[8][8] = (float(*)[8][8])sRaw;
  const int t = threadIdx.x;
  const int e0 = blockIdx.x * 32;
  if (t < 32) {
    unsigned e = eid[e0 + t];
    s_eid[t] = e;
    s_src[t] = eidx[e];
    s_dst[t] = eidx[N_EDGES + e];
    const float* ea = eattr + (size_t)e * 7;
    s_ea[t][0] = ea[0]; s_ea[t][1] = ea[1]; s_ea[t][2] = ea[2];
  }
  __syncthreads();
  const int i = t & 31, seg = t >> 5;  // 32 edges x 8 segs of 16 cols
  const int lane = t & 63, wave = t >> 6;
  const int lrow = lane & 15, quad = lane >> 4;
  const int wcol = wave * 64;  // each wave owns 64 of 256 output cols per m
  h2 ea0h, ea1h, ea2h;
  ea0h[0] = ea0h[1] = (_Float16)s_ea[i][0];
  ea1h[0] = ea1h[1] = (_Float16)s_ea[i][1];
  ea2h[0] = ea2h[1] = (_Float16)s_ea[i][2];
  const u8* ABs = AB + (size_t)s_src[i] * 3072 + seg * 16;
  const u8* ABd = AB + (size_t)s_dst[i] * 3072 + 1536 + seg * 16;
  // flat chunk loop c = m*4 + q; rolled (unroll 1) to keep registers bounded.
  uint4 cs, cd, ns, nd;
  cs = *(const uint4*)(ABs);
  cd = *(const uint4*)(ABd);
  f32x4 acc[2][4];
#pragma unroll 1
  for (int c = 0; c < 12; ++c) {
    const int m = c >> 2, q = c & 3;
    const int k0 = q * 128;
    if (q == 0) {
      const f32x4 z = {0.f, 0.f, 0.f, 0.f};
#pragma unroll
      for (int i2 = 0; i2 < 2; ++i2)
#pragma unroll
        for (int j = 0; j < 4; ++j) acc[i2][j] = z;
    }
    if (c < 11) {  // prefetch next chunk's 2x16B gathers (hide under assemble+MFMA)
      const int cn = c + 1;
      ns = *(const uint4*)(ABs + (cn >> 2) * 512 + (cn & 3) * 128);
      nd = *(const uint4*)(ABd + (cn >> 2) * 512 + (cn & 3) * 128);
    }
    {  // assemble 16 cols per thread: edge i, cols [k0+seg*16, +16) from prefetched regs
      const unsigned* w32 = (const unsigned*)(w1e16 + (size_t)m * 1536);
      alignas(16) unsigned sd[4], dd[4];
      *(uint4*)&sd[0] = cs;
      *(uint4*)&dd[0] = cd;
      const int cp0 = (k0 + seg * 16) >> 1;
      alignas(16) unsigned hout[8];
#pragma unroll
      for (int d = 0; d < 4; ++d) {
        int cp = cp0 + d * 2;
        h2 slo = e5lo(sd[d]) + e5lo(dd[d]);
        h2 shi = e5hi(sd[d]) + e5hi(dd[d]);
        slo += ea0h * __builtin_bit_cast(h2, w32[cp]);
        shi += ea0h * __builtin_bit_cast(h2, w32[cp + 1]);
        slo += ea1h * __builtin_bit_cast(h2, w32[256 + cp]);
        shi += ea1h * __builtin_bit_cast(h2, w32[256 + cp + 1]);
        slo += ea2h * __builtin_bit_cast(h2, w32[512 + cp]);
        shi += ea2h * __builtin_bit_cast(h2, w32[512 + cp + 1]);
        float g0 = gelu_s((float)slo[0]), g1 = gelu_s((float)slo[1]);
        float g2 = gelu_s((float)shi[0]), g3 = gelu_s((float)shi[1]);
        hout[d * 2] = (unsigned)f2h(g0) | ((unsigned)f2h(g1) << 16);
        hout[d * 2 + 1] = (unsigned)f2h(g2) | ((unsigned)f2h(g3) << 16);
      }
      uint4* hp = (uint4*)&sH[i][seg * 16];
      hp[0] = *(const uint4*)&hout[0];
      hp[1] = *(const uint4*)&hout[4];
    }
    __syncthreads();
    {  // MFMA: 2 row-groups x 4 col-groups; each 16B W2T load feeds 2 MFMAs
      const u16* Wm = W2T + (size_t)(m * 256 + wcol) * 512;
#pragma unroll
      for (int ks = 0; ks < 4; ++ks) {
        int kk = ks * 32;
        v8h a0 = *(const v8h*)&sH[lrow][kk + quad * 8];
        v8h a1 = *(const v8h*)&sH[16 + lrow][kk + quad * 8];
#pragma unroll
        for (int j = 0; j < 4; ++j) {
          v8h b = *(const v8h*)&Wm[(size_t)(j * 16 + lrow) * 512 + k0 + kk + quad * 8];
          acc[0][j] = __builtin_amdgcn_mfma_f32_16x16x32_f16(a0, b, acc[0][j], 0, 0, 0);
          acc[1][j] = __builtin_amdgcn_mfma_f32_16x16x32_f16(a1, b, acc[1][j], 0, 0, 0);
        }
      }
    }
    __syncthreads();
    cs = ns;
    cd = nd;
    if (q == 3) {  // epilogue for m: +b2, e5m2-encode into sQ (this m's 256-byte slice)
      const float* b2 = (m == 0) ? qb2 : (m == 1) ? kb2 : vb2;
#pragma unroll
      for (int i2 = 0; i2 < 2; ++i2)
#pragma unroll
        for (int j = 0; j < 4; ++j)
#pragma unroll
          for (int rg = 0; rg < 4; ++rg) {
            int row = i2 * 16 + quad * 4 + rg;
            int col = wcol + j * 16 + lrow;
            sQ[row][m * 256 + col] = f2e5m2(acc[i2][j][rg] + b2[col]);
          }
    }
  }
  __syncthreads();  // sQ complete; sH dead -> sS aliases it
  // ---------------- attention phase: 256 threads = 32 edges x 8 heads ----------------
  const int hh = t & 7, ii = t >> 3;
  {
    alignas(16) unsigned qd[8];
    *(uint4*)&qd[0] = *(const uint4*)&sQ[ii][hh * 32];
    *(uint4*)&qd[4] = *(const uint4*)&sQ[ii][hh * 32 + 16];
    h2 qh[16];
#pragma unroll
    for (int d = 0; d < 8; ++d) { qh[d * 2] = e5lo(qd[d]); qh[d * 2 + 1] = e5hi(qd[d]); }
    float bias = biasb[(size_t)s_eid[ii] * 8 + hh];
    float sc[8];
#pragma unroll
    for (int g = 0; g < 8; ++g) {
      alignas(16) unsigned kd[8];
      *(uint4*)&kd[0] = *(const uint4*)&sQ[ii][256 + g * 32];
      *(uint4*)&kd[4] = *(const uint4*)&sQ[ii][256 + g * 32 + 16];
      h2 acc2;
      acc2[0] = acc2[1] = (_Float16)0.f;
#pragma unroll
      for (int d = 0; d < 8; ++d) {
        acc2 += qh[d * 2] * e5lo(kd[d]);
        acc2 += qh[d * 2 + 1] * e5hi(kd[d]);
      }
      sc[g] = (float)acc2[0] + (float)acc2[1];
    }
#pragma unroll
    for (int g = 0; g < 8; ++g) sS[ii][hh][g] = sc[g] * 0.17677669529663687f + bias;
  }
  __syncthreads();
  {  // softmax over h (axis=1) per (edge, g=hh)
    const int g = hh;
    float mx = -1e30f;
#pragma unroll
    for (int h2i = 0; h2i < 8; ++h2i) mx = fmaxf(mx, sS[ii][h2i][g]);
    float ev[8], ssum = 0.f;
#pragma unroll
    for (int h2i = 0; h2i < 8; ++h2i) {
      ev[h2i] = __expf(sS[ii][h2i][g] - mx);
      ssum += ev[h2i];
    }
    float inv = 1.0f / ssum;
#pragma unroll
    for (int h2i = 0; h2i < 8; ++h2i) sS[ii][h2i][g] = ev[h2i] * inv;
  }
  __syncthreads();
  {  // wv[sorted pos][hh*32..] = sum_g attn[hh][g]*V[g][:]
    h2 va[16];
#pragma unroll
    for (int u = 0; u < 16; ++u) va[u][0] = va[u][1] = (_Float16)0.f;
#pragma unroll
    for (int g = 0; g < 8; ++g) {
      float at = sS[ii][hh][g];
      h2 at2;
      at2[0] = at2[1] = (_Float16)at;
      alignas(16) unsigned vd[8];
      *(uint4*)&vd[0] = *(const uint4*)&sQ[ii][512 + g * 32];
      *(uint4*)&vd[4] = *(const uint4*)&sQ[ii][512 + g * 32 + 16];
#pragma unroll
      for (int d = 0; d < 8; ++d) {
        va[d * 2] += at2 * e5lo(vd[d]);
        va[d * 2 + 1] += at2 * e5hi(vd[d]);
      }
    }
    alignas(16) unsigned od[8];
#pragma unroll
    for (int p = 0; p < 8; ++p) {
      unsigned a = __builtin_bit_cast(unsigned, va[p * 2]) + 0x00800080u;
      unsigned b = __builtin_bit_cast(unsigned, va[p * 2 + 1]) + 0x00800080u;
      od[p] = __builtin_amdgcn_perm(b, a, 0x07050301u);
    }
    u8* dp = wv + (size_t)(e0 + ii) * 256 + hh * 32;
    *(uint4*)dp = *(const uint4*)&od[0];
    *(uint4*)(dp + 16) = *(const uint4*)&od[4];
  }
}

// ---------------- node gather-mean + x1/X1cat build (wv in dst-sorted order) ------------
__global__ __launch_bounds__(256) void node_gather(const unsigned* __restrict__ off,
                                                   const unsigned* __restrict__ cnt,
                                                   const u8* __restrict__ wv,
                                                   const float* __restrict__ x,
                                                   float* __restrict__ x1,
                                                   u16* __restrict__ X1cat) {
  int n = blockIdx.x * 4 + (threadIdx.x >> 6);
  int lane = threadIdx.x & 63;
  unsigned st = off[n], c = cnt[n];
  float a0 = 0.f, a1 = 0.f, a2 = 0.f, a3 = 0.f;
  for (unsigned j = 0; j < c; ++j) {
    unsigned d = *(const unsigned*)(wv + (size_t)(st + j) * 256 + lane * 4);
    float f[4];
    dec4(d, f);
    a0 += f[0]; a1 += f[1]; a2 += f[2]; a3 += f[3];
  }
  float inv = 1.0f / fmaxf((float)c, 1.0f);
  float4 xv = *(const float4*)(x + (size_t)n * 256 + lane * 4);
  float4 x1v = {xv.x + a0 * inv, xv.y + a1 * inv, xv.z + a2 * inv, xv.w + a3 * inv};
  *(float4*)(x1 + (size_t)n * 256 + lane * 4) = x1v;
  ushort4 a, bq;
  a.x = f2h(x1v.x); a.y = f2h(x1v.y); a.z = f2h(x1v.z); a.w = f2h(x1v.w);
  bq.x = f2h(xv.x); bq.y = f2h(xv.y); bq.z = f2h(xv.z); bq.w = f2h(xv.w);
  *(ushort4*)(X1cat + (size_t)n * 512 + lane * 4) = a;
  *(ushort4*)(X1cat + (size_t)n * 512 + 256 + lane * 4) = bq;
}

extern "C" void kernel_launch(void* const* d_in, const int* in_sizes, int n_in,
                              void* d_out, int out_size, void* d_ws, size_t ws_size,
                              hipStream_t stream) {
  const float* x = (const float*)d_in[0];
  const int* eidx = (const int*)d_in[1];
  const float* eattr = (const float*)d_in[2];
  const float* qW1 = (const float*)d_in[3];
  const float* qb1 = (const float*)d_in[4];
  const float* qW2 = (const float*)d_in[5];
  const float* qb2 = (const float*)d_in[6];
  const float* kW1 = (const float*)d_in[7];
  const float* kb1 = (const float*)d_in[8];
  const float* kW2 = (const float*)d_in[9];
  const float* kb2 = (const float*)d_in[10];
  const float* vW1 = (const float*)d_in[11];
  const float* vb1 = (const float*)d_in[12];
  const float* vW2 = (const float*)d_in[13];
  const float* vb2 = (const float*)d_in[14];
  const float* sW1 = (const float*)d_in[15];
  const float* sb1 = (const float*)d_in[16];
  const float* sW2 = (const float*)d_in[17];
  const float* sb2 = (const float*)d_in[18];
  const float* fW1 = (const float*)d_in[19];
  const float* fb1 = (const float*)d_in[20];
  const float* fW2 = (const float*)d_in[21];
  const float* fb2 = (const float*)d_in[22];
  const float* lng = (const float*)d_in[23];
  const float* lnb = (const float*)d_in[24];
  const float* rW = (const float*)d_in[25];
  const float* rb = (const float*)d_in[26];

  const size_t N = N_NODES;
  char* ws = (char*)d_ws;
  size_t off_b = 0;
  auto alloc = [&](size_t bytes) {
    void* p = ws + off_b;
    off_b = (off_b + bytes + 255) & ~(size_t)255;
    return p;
  };
  u16* W1catT = (u16*)alloc((size_t)3072 * 256 * 2);
  u16* W2T = (u16*)alloc((size_t)768 * 512 * 2);
  u16* rWT = (u16*)alloc((size_t)256 * 512 * 2);
  u16* fW1T = (u16*)alloc((size_t)512 * 256 * 2);
  u16* fW2T = (u16*)alloc((size_t)256 * 512 * 2);
  u16* w1e16 = (u16*)alloc((size_t)9 * 512 * 2);
  float* b1cat = (float*)alloc((size_t)1536 * 4);
  unsigned* cnt = (unsigned*)alloc(N * 4);
  unsigned* offs = (unsigned*)alloc(N * 4);
  unsigned* woff = (unsigned*)alloc(N * 4);
  unsigned* eid = (unsigned*)alloc((size_t)N_EDGES * 4);
  float* biasb = (float*)alloc((size_t)N_EDGES * 8 * 4);  // 8.4 MB s-MLP bias
  u8* AB = (u8*)alloc(N * 3072);  // e5m2, 201 MB; node-stage aliases below
  // xn (fp16 LN output, 33.5 MB) and wv (fp8 per-edge, 67 MB) both live in d_out;
  // xn is dead before qkv_attn writes wv.
  u16* xn = (u16*)d_out;
  u8* wv = (u8*)d_out;
  float* x1 = (float*)AB;                        // 64 MB
  u16* X1cat = (u16*)(AB + (size_t)67108864);    // 64 MB
  float* x2 = (float*)(AB + (size_t)134217728);  // 64 MB
  u16* xn2 = (u16*)AB;                           // 32 MB (x1 dead)
  u16* Hf = (u16*)(AB + (size_t)33554432);       // 64 MB (X1cat dead)

  hipMemsetAsync(cnt, 0, N * 4, stream);
  hist_kernel<<<N_EDGES / 256, 256, 0, stream>>>(eidx + N_EDGES, cnt);
  scan_kernel<<<1, 1024, 0, stream>>>(cnt, offs, woff);
  scatter_ids<<<N_EDGES / 256, 256, 0, stream>>>(eidx + N_EDGES, woff, eid);
  prep_w1catT<<<3072, 256, 0, stream>>>(W1catT, qW1, kW1, vW1);
  prep_w2T<<<768, 256, 0, stream>>>(W2T, qW2, kW2, vW2);
  prep_w1e16<<<9, 512, 0, stream>>>(w1e16, qW1, kW1, vW1);
  prep_b1cat<<<6, 256, 0, stream>>>(b1cat, qb1, kb1, vb1);
  transpose_cast<<<256, 256, 0, stream>>>(rWT, rW, 512, 256);
  transpose_cast<<<512, 256, 0, stream>>>(fW1T, fW1, 256, 512);
  transpose_cast<<<256, 256, 0, stream>>>(fW2T, fW2, 512, 256);
  bias_kernel<<<N_EDGES / 256, 256, 0, stream>>>(eattr, sW1, sb1, sW2, sb2, biasb);

  ln_kernel<<<N_NODES / 4, 256, 0, stream>>>(x, lng, lnb, xn);
  gemm2_ab<<<12288, 256, 0, stream>>>(xn, W1catT, b1cat, AB);
  qkv_attn<<<N_EDGES / 32, 256, 0, stream>>>(eidx, eattr, eid, AB, W2T, w1e16,
                                             qb2, kb2, vb2, biasb, wv);
  node_gather<<<N_NODES / 4, 256, 0, stream>>>(offs, cnt, wv, x, x1, X1cat);
  gemm_bt<<<dim3(N_NODES / 128, 2), 256, 0, stream>>>(X1cat, rWT, 512, EpiX2{x2, x1, rb});
  ln_kernel<<<N_NODES / 4, 256, 0, stream>>>(x2, lng, lnb, xn2);
  gemm_bt<<<dim3(N_NODES / 128, 4), 256, 0, stream>>>(xn2, fW1T, 256, EpiHf{Hf, fb1});
  gemm_bt<<<dim3(N_NODES / 128, 2), 256, 0, stream>>>(Hf, fW2T, 512, EpiOut{(float*)d_out, fb2, x2});
}